// Round 1
// baseline (1002.409 us; speedup 1.0000x reference)
//
#include <hip/hip_runtime.h>
#include <hip/hip_bf16.h>

// Swin block, fused: prep (weights->bf16^T, bias/mask tables) + windowed
// attention megakernel (LN1+roll+QKV+attn+proj+residual) + MLP megakernel
// (LN2+FC1+GELU+FC2+residual, in-place on d_out).

using f32x4  = __attribute__((ext_vector_type(4))) float;
using short8 = __attribute__((ext_vector_type(8))) short;
typedef unsigned short ushort_t;

__device__ __forceinline__ ushort_t f2bf(float f) {
    __hip_bfloat16 h = __float2bfloat16(f);
    return __builtin_bit_cast(ushort_t, h);
}

__device__ __forceinline__ f32x4 mfma16(short8 a, short8 b, f32x4 c) {
    return __builtin_amdgcn_mfma_f32_16x16x32_bf16(a, b, c, 0, 0, 0);
}

// ---------------- sizes ----------------
#define BB 32
#define HH 56
#define CC 192
#define NWIN 64          // windows per image (8x8)
#define NTOK 49
#define NHEAD 6
#define HIDDEN 768

// ws offsets (bytes)
#define OFF_QKVT   0          // [576][192] bf16
#define OFF_PROJT  221184     // [192][192] bf16
#define OFF_FC1T   294912     // [768][192] bf16
#define OFF_FC2T   589824     // [192][768] bf16
#define OFF_BIAS   884736     // [6][49][49] f32
#define OFF_MASK   942592     // [64][49][49] f32
#define PREP_TOTAL (110592 + 36864 + 147456 + 147456 + 14406 + 153664)

// ---------------- prep ----------------
__global__ void prep_kernel(const float* __restrict__ qkv_w, const float* __restrict__ proj_w,
                            const float* __restrict__ fc1_w, const float* __restrict__ fc2_w,
                            const float* __restrict__ rel_table,
                            ushort_t* __restrict__ qkvT, ushort_t* __restrict__ projT,
                            ushort_t* __restrict__ fc1T, ushort_t* __restrict__ fc2T,
                            float* __restrict__ biasT, float* __restrict__ maskT) {
    int idx = blockIdx.x * 256 + threadIdx.x;
    if (idx < 110592) { int n = idx / 192, k = idx % 192; qkvT[idx] = f2bf(qkv_w[k * 576 + n]); return; }
    idx -= 110592;
    if (idx < 36864) { int n = idx / 192, k = idx % 192; projT[idx] = f2bf(proj_w[k * 192 + n]); return; }
    idx -= 36864;
    if (idx < 147456) { int n = idx / 192, k = idx % 192; fc1T[idx] = f2bf(fc1_w[k * 768 + n]); return; }
    idx -= 147456;
    if (idx < 147456) { int n = idx / 768, k = idx % 768; fc2T[idx] = f2bf(fc2_w[k * 192 + n]); return; }
    idx -= 147456;
    if (idx < 14406) {
        int h = idx / 2401; int rest = idx % 2401; int a = rest / 49, b = rest % 49;
        int d = 13 * ((a % 7) - (b % 7) + (a / 7) - (b / 7) + 12);
        if (d > 168) d = 168;
        biasT[idx] = rel_table[d * 6 + h];
        return;
    }
    idx -= 14406;
    if (idx < 153664) {
        int w = idx / 2401; int rest = idx % 2401; int a = rest / 49, b = rest % 49;
        int wy = w / 8, wx = w % 8;
        int ya = wy * 7 + a / 7, xa = wx * 7 + a % 7;
        int yb = wy * 7 + b / 7, xb = wx * 7 + b % 7;
        int lya = ya < 49 ? 0 : (ya < 53 ? 1 : 2);
        int lxa = xa < 49 ? 0 : (xa < 53 ? 1 : 2);
        int lyb = yb < 49 ? 0 : (yb < 53 ? 1 : 2);
        int lxb = xb < 49 ? 0 : (xb < 53 ? 1 : 2);
        maskT[idx] = ((lya * 3 + lxa) != (lyb * 3 + lxb)) ? -100.0f : 0.0f;
        return;
    }
}

// ---------------- attention megakernel ----------------
// 1 block per window (2048 blocks), 256 threads (4 waves).
// LDS layout (dynamic, 131328 B):
//   xln  [64][192] bf16 @ 0        (LN1 rows, zero-padded rows 49..63)
//   qkvs [64][576] bf16 @ 24576    (QKV; cols 0..191 reused as attn-out O)
//   vt   [6][32][64] bf16 @ 98304  (V transposed per head, zero-padded k>=49)
//   Pl   [64][64]  bf16 @ 122880   (softmax probabilities)
//   grow [64] int @ 131072         (global row index per token)
__global__ __launch_bounds__(256) void attn_kernel(
    const float* __restrict__ x, const float* __restrict__ n1g, const float* __restrict__ n1b,
    const float* __restrict__ qkv_b, const float* __restrict__ proj_b,
    const ushort_t* __restrict__ qkvT, const ushort_t* __restrict__ projT,
    const float* __restrict__ biasT, const float* __restrict__ maskT,
    float* __restrict__ out) {
    extern __shared__ char smem[];
    ushort_t* xln  = (ushort_t*)smem;
    ushort_t* qkvs = (ushort_t*)(smem + 24576);
    ushort_t* vt   = (ushort_t*)(smem + 98304);
    ushort_t* Pl   = (ushort_t*)(smem + 122880);
    int* grow      = (int*)(smem + 131072);

    const int tid = threadIdx.x;
    const int wave = tid >> 6, lane = tid & 63;
    const int ln16 = lane & 15, sub = lane >> 4;
    const int w = blockIdx.x;
    const int batch = w >> 6, wi = w & 63;
    const int wy = wi >> 3, wx = wi & 7;
    const f32x4 zero4 = {0.f, 0.f, 0.f, 0.f};

    // ---- phase 0: gather + LN1 (and zero-pad rows) ----
    for (int j = wave; j < 64; j += 4) {
        if (j < 49) {
            int ty = j / 7, tx = j % 7;
            int y = (wy * 7 + ty + 3) % 56;
            int xx = (wx * 7 + tx + 3) % 56;
            int g = batch * 3136 + y * 56 + xx;
            if (lane == 0) grow[j] = g;
            const float* xr = x + (size_t)g * CC;
            float v0 = xr[lane], v1 = xr[lane + 64], v2 = xr[lane + 128];
            float s = v0 + v1 + v2;
            #pragma unroll
            for (int m = 32; m; m >>= 1) s += __shfl_xor(s, m);
            float mu = s * (1.0f / 192.0f);
            float d0 = v0 - mu, d1 = v1 - mu, d2 = v2 - mu;
            float q = d0 * d0 + d1 * d1 + d2 * d2;
            #pragma unroll
            for (int m = 32; m; m >>= 1) q += __shfl_xor(q, m);
            float rs = rsqrtf(q * (1.0f / 192.0f) + 1e-5f);
            xln[j * 192 + lane]       = f2bf(d0 * rs * n1g[lane]       + n1b[lane]);
            xln[j * 192 + lane + 64]  = f2bf(d1 * rs * n1g[lane + 64]  + n1b[lane + 64]);
            xln[j * 192 + lane + 128] = f2bf(d2 * rs * n1g[lane + 128] + n1b[lane + 128]);
        } else {
            xln[j * 192 + lane] = 0; xln[j * 192 + lane + 64] = 0; xln[j * 192 + lane + 128] = 0;
        }
    }
    for (int i = tid; i < 6 * 32 * 64; i += 256) vt[i] = 0;
    __syncthreads();

    // ---- phase 1: QKV GEMM [64,192]x[192,576] ----
    for (int m = 0; m < 4; ++m) {
        f32x4 acc[9];
        #pragma unroll
        for (int n = 0; n < 9; ++n) acc[n] = zero4;
        for (int k = 0; k < 6; ++k) {
            short8 a = *(const short8*)(xln + (m * 16 + ln16) * 192 + k * 32 + 8 * sub);
            #pragma unroll
            for (int n = 0; n < 9; ++n) {
                short8 bb = *(const short8*)(qkvT + (size_t)((wave * 9 + n) * 16 + ln16) * 192 + k * 32 + 8 * sub);
                acc[n] = mfma16(a, bb, acc[n]);
            }
        }
        #pragma unroll
        for (int n = 0; n < 9; ++n) {
            int col = (wave * 9 + n) * 16 + ln16;
            float bias = qkv_b[col];
            #pragma unroll
            for (int r = 0; r < 4; ++r) {
                int row = m * 16 + 4 * sub + r;
                ushort_t hv = f2bf(acc[n][r] + bias);
                qkvs[row * 576 + col] = hv;
                if (col >= 384 && row < 49) {
                    int hh = (col - 384) >> 5, vc = (col - 384) & 31;
                    vt[hh * 2048 + vc * 64 + row] = hv;
                }
            }
        }
    }
    __syncthreads();

    // ---- phase 2: attention (wave handles m-tile == wave) ----
    const float scale = 0.17677669529663689f;
    for (int h = 0; h < 6; ++h) {
        f32x4 s[4];
        {
            short8 aq = *(const short8*)(qkvs + (wave * 16 + ln16) * 576 + h * 32 + 8 * sub);
            #pragma unroll
            for (int n = 0; n < 4; ++n) {
                short8 bk = *(const short8*)(qkvs + (n * 16 + ln16) * 576 + 192 + h * 32 + 8 * sub);
                s[n] = mfma16(aq, bk, zero4);
            }
        }
        #pragma unroll
        for (int n = 0; n < 4; ++n) {
            int col = n * 16 + ln16;
            #pragma unroll
            for (int r = 0; r < 4; ++r) {
                int row = wave * 16 + 4 * sub + r;
                float v;
                if (row < 49 && col < 49)
                    v = s[n][r] * scale + biasT[h * 2401 + row * 49 + col] + maskT[wi * 2401 + row * 49 + col];
                else
                    v = -1e30f;
                s[n][r] = v;
            }
        }
        #pragma unroll
        for (int r = 0; r < 4; ++r) {
            float mx = fmaxf(fmaxf(s[0][r], s[1][r]), fmaxf(s[2][r], s[3][r]));
            mx = fmaxf(mx, __shfl_xor(mx, 1, 16));
            mx = fmaxf(mx, __shfl_xor(mx, 2, 16));
            mx = fmaxf(mx, __shfl_xor(mx, 4, 16));
            mx = fmaxf(mx, __shfl_xor(mx, 8, 16));
            float e0 = __expf(s[0][r] - mx), e1 = __expf(s[1][r] - mx);
            float e2 = __expf(s[2][r] - mx), e3 = __expf(s[3][r] - mx);
            float sm = e0 + e1 + e2 + e3;
            sm += __shfl_xor(sm, 1, 16);
            sm += __shfl_xor(sm, 2, 16);
            sm += __shfl_xor(sm, 4, 16);
            sm += __shfl_xor(sm, 8, 16);
            float inv = 1.0f / sm;
            int row = wave * 16 + 4 * sub + r;
            Pl[row * 64 +      ln16] = f2bf(e0 * inv);
            Pl[row * 64 + 16 + ln16] = f2bf(e1 * inv);
            Pl[row * 64 + 32 + ln16] = f2bf(e2 * inv);
            Pl[row * 64 + 48 + ln16] = f2bf(e3 * inv);
        }
        __syncthreads();
        f32x4 o2[2]; o2[0] = zero4; o2[1] = zero4;
        #pragma unroll
        for (int ks = 0; ks < 2; ++ks) {
            short8 ap = *(const short8*)(Pl + (wave * 16 + ln16) * 64 + ks * 32 + 8 * sub);
            #pragma unroll
            for (int n2 = 0; n2 < 2; ++n2) {
                short8 bv = *(const short8*)(vt + h * 2048 + (n2 * 16 + ln16) * 64 + ks * 32 + 8 * sub);
                o2[n2] = mfma16(ap, bv, o2[n2]);
            }
        }
        #pragma unroll
        for (int n2 = 0; n2 < 2; ++n2)
            #pragma unroll
            for (int r = 0; r < 4; ++r) {
                int row = wave * 16 + 4 * sub + r;
                qkvs[row * 576 + h * 32 + n2 * 16 + ln16] = f2bf(o2[n2][r]);
            }
        __syncthreads();
    }

    // ---- phase 3: proj + residual, scatter to out ----
    f32x4 acc[12];
    #pragma unroll
    for (int n = 0; n < 12; ++n) acc[n] = zero4;
    for (int k = 0; k < 6; ++k) {
        short8 a = *(const short8*)(qkvs + (wave * 16 + ln16) * 576 + k * 32 + 8 * sub);
        #pragma unroll
        for (int n = 0; n < 12; ++n) {
            short8 bb = *(const short8*)(projT + (size_t)(n * 16 + ln16) * 192 + k * 32 + 8 * sub);
            acc[n] = mfma16(a, bb, acc[n]);
        }
    }
    #pragma unroll
    for (int n = 0; n < 12; ++n) {
        int col = n * 16 + ln16;
        float pb = proj_b[col];
        #pragma unroll
        for (int r = 0; r < 4; ++r) {
            int row = wave * 16 + 4 * sub + r;
            if (row < 49) {
                int g = grow[row];
                out[(size_t)g * CC + col] = acc[n][r] + pb + x[(size_t)g * CC + col];
            }
        }
    }
}

// ---------------- MLP megakernel ----------------
// 32 tokens per block (3136 blocks), 256 threads. In-place on out.
__global__ __launch_bounds__(256) void mlp_kernel(
    float* __restrict__ out, const float* __restrict__ n2g, const float* __restrict__ n2b,
    const float* __restrict__ fc1_b, const float* __restrict__ fc2_b,
    const ushort_t* __restrict__ fc1T, const ushort_t* __restrict__ fc2T) {
    __shared__ ushort_t aln[32 * 192];
    __shared__ ushort_t hid[32 * 768];
    const int tid = threadIdx.x;
    const int wave = tid >> 6, lane = tid & 63;
    const int ln16 = lane & 15, sub = lane >> 4;
    const size_t t0 = (size_t)blockIdx.x * 32;
    const f32x4 zero4 = {0.f, 0.f, 0.f, 0.f};

    for (int r = wave; r < 32; r += 4) {
        const float* xr = out + (t0 + r) * CC;
        float v0 = xr[lane], v1 = xr[lane + 64], v2 = xr[lane + 128];
        float s = v0 + v1 + v2;
        #pragma unroll
        for (int m = 32; m; m >>= 1) s += __shfl_xor(s, m);
        float mu = s * (1.0f / 192.0f);
        float d0 = v0 - mu, d1 = v1 - mu, d2 = v2 - mu;
        float q = d0 * d0 + d1 * d1 + d2 * d2;
        #pragma unroll
        for (int m = 32; m; m >>= 1) q += __shfl_xor(q, m);
        float rs = rsqrtf(q * (1.0f / 192.0f) + 1e-5f);
        aln[r * 192 + lane]       = f2bf(d0 * rs * n2g[lane]       + n2b[lane]);
        aln[r * 192 + lane + 64]  = f2bf(d1 * rs * n2g[lane + 64]  + n2b[lane + 64]);
        aln[r * 192 + lane + 128] = f2bf(d2 * rs * n2g[lane + 128] + n2b[lane + 128]);
    }
    __syncthreads();

    // FC1 + GELU
    f32x4 acc[2][12];
    #pragma unroll
    for (int m = 0; m < 2; ++m)
        #pragma unroll
        for (int n = 0; n < 12; ++n) acc[m][n] = zero4;
    for (int k = 0; k < 6; ++k) {
        short8 a0 = *(const short8*)(aln + ln16 * 192 + k * 32 + 8 * sub);
        short8 a1 = *(const short8*)(aln + (16 + ln16) * 192 + k * 32 + 8 * sub);
        #pragma unroll
        for (int n = 0; n < 12; ++n) {
            short8 bb = *(const short8*)(fc1T + (size_t)((wave * 12 + n) * 16 + ln16) * 192 + k * 32 + 8 * sub);
            acc[0][n] = mfma16(a0, bb, acc[0][n]);
            acc[1][n] = mfma16(a1, bb, acc[1][n]);
        }
    }
    #pragma unroll
    for (int m = 0; m < 2; ++m)
        #pragma unroll
        for (int n = 0; n < 12; ++n) {
            int col = (wave * 12 + n) * 16 + ln16;
            float fb = fc1_b[col];
            #pragma unroll
            for (int r = 0; r < 4; ++r) {
                int row = m * 16 + 4 * sub + r;
                float hv = acc[m][n][r] + fb;
                float ge = 0.5f * hv * (1.0f + erff(hv * 0.70710678118654752f));
                hid[row * 768 + col] = f2bf(ge);
            }
        }
    __syncthreads();

    // FC2 + residual (in place)
    f32x4 acc2[2][3];
    #pragma unroll
    for (int m = 0; m < 2; ++m)
        #pragma unroll
        for (int n = 0; n < 3; ++n) acc2[m][n] = zero4;
    for (int k = 0; k < 24; ++k) {
        short8 a0 = *(const short8*)(hid + ln16 * 768 + k * 32 + 8 * sub);
        short8 a1 = *(const short8*)(hid + (16 + ln16) * 768 + k * 32 + 8 * sub);
        #pragma unroll
        for (int n = 0; n < 3; ++n) {
            short8 bb = *(const short8*)(fc2T + (size_t)((wave * 3 + n) * 16 + ln16) * 768 + k * 32 + 8 * sub);
            acc2[0][n] = mfma16(a0, bb, acc2[0][n]);
            acc2[1][n] = mfma16(a1, bb, acc2[1][n]);
        }
    }
    #pragma unroll
    for (int m = 0; m < 2; ++m)
        #pragma unroll
        for (int n = 0; n < 3; ++n) {
            int col = (wave * 3 + n) * 16 + ln16;
            float fb = fc2_b[col];
            #pragma unroll
            for (int r = 0; r < 4; ++r) {
                int row = m * 16 + 4 * sub + r;
                size_t o = (t0 + row) * CC + col;
                out[o] = acc2[m][n][r] + fb + out[o];
            }
        }
}

// ---------------- launch ----------------
extern "C" void kernel_launch(void* const* d_in, const int* in_sizes, int n_in,
                              void* d_out, int out_size, void* d_ws, size_t ws_size,
                              hipStream_t stream) {
    const float* x      = (const float*)d_in[0];
    const float* n1g    = (const float*)d_in[1];
    const float* n1b    = (const float*)d_in[2];
    const float* qkv_w  = (const float*)d_in[3];
    const float* qkv_b  = (const float*)d_in[4];
    const float* rel_t  = (const float*)d_in[5];
    const float* proj_w = (const float*)d_in[6];
    const float* proj_b = (const float*)d_in[7];
    const float* n2g    = (const float*)d_in[8];
    const float* n2b    = (const float*)d_in[9];
    const float* fc1_w  = (const float*)d_in[10];
    const float* fc1_b  = (const float*)d_in[11];
    const float* fc2_w  = (const float*)d_in[12];
    const float* fc2_b  = (const float*)d_in[13];
    float* out = (float*)d_out;

    char* ws = (char*)d_ws;
    ushort_t* qkvT  = (ushort_t*)(ws + OFF_QKVT);
    ushort_t* projT = (ushort_t*)(ws + OFF_PROJT);
    ushort_t* fc1T  = (ushort_t*)(ws + OFF_FC1T);
    ushort_t* fc2T  = (ushort_t*)(ws + OFF_FC2T);
    float* biasT    = (float*)(ws + OFF_BIAS);
    float* maskT    = (float*)(ws + OFF_MASK);

    int prep_blocks = (PREP_TOTAL + 255) / 256;
    prep_kernel<<<prep_blocks, 256, 0, stream>>>(qkv_w, proj_w, fc1_w, fc2_w, rel_t,
                                                 qkvT, projT, fc1T, fc2T, biasT, maskT);

    static int smem_set = 0;
    (void)smem_set;
    hipFuncSetAttribute((const void*)attn_kernel,
                        hipFuncAttributeMaxDynamicSharedMemorySize, 131328);
    attn_kernel<<<2048, 256, 131328, stream>>>(x, n1g, n1b, qkv_b, proj_b,
                                               qkvT, projT, biasT, maskT, out);

    mlp_kernel<<<3136, 256, 0, stream>>>(out, n2g, n2b, fc1_b, fc2_b, fc1T, fc2T);
}

// Round 2
// 962.723 us; speedup vs baseline: 1.0412x; 1.0412x over previous
//
#include <hip/hip_runtime.h>
#include <hip/hip_bf16.h>

// Swin block, fused. Round 2: occupancy + bank-conflict rework.
//  - attn: per-head QKV/attn/proj-accumulate, LDS 48.5 KB, 3 blocks/CU.
//  - mlp: 64 tokens/block, hidden chunked by 128, barrier-free, 43 KB LDS.

using f32x4  = __attribute__((ext_vector_type(4))) float;
using short8 = __attribute__((ext_vector_type(8))) short;
typedef unsigned short ushort_t;

__device__ __forceinline__ ushort_t f2bf(float f) {
    __hip_bfloat16 h = __float2bfloat16(f);
    return __builtin_bit_cast(ushort_t, h);
}
__device__ __forceinline__ f32x4 mfma16(short8 a, short8 b, f32x4 c) {
    return __builtin_amdgcn_mfma_f32_16x16x32_bf16(a, b, c, 0, 0, 0);
}

#define CC 192

// ws offsets (bytes)
#define OFF_QKVT   0          // [576][192] bf16
#define OFF_PROJT  221184     // [192][192] bf16
#define OFF_FC1T   294912     // [768][192] bf16
#define OFF_FC2T   589824     // [192][768] bf16
#define OFF_BIAS   884736     // [6][49][49] f32
#define OFF_MASK   942592     // [64][49][49] f32
#define PREP_TOTAL (110592 + 36864 + 147456 + 147456 + 14406 + 153664)

// ---------------- prep ----------------
__global__ void prep_kernel(const float* __restrict__ qkv_w, const float* __restrict__ proj_w,
                            const float* __restrict__ fc1_w, const float* __restrict__ fc2_w,
                            const float* __restrict__ rel_table,
                            ushort_t* __restrict__ qkvT, ushort_t* __restrict__ projT,
                            ushort_t* __restrict__ fc1T, ushort_t* __restrict__ fc2T,
                            float* __restrict__ biasT, float* __restrict__ maskT) {
    int idx = blockIdx.x * 256 + threadIdx.x;
    if (idx < 110592) { int n = idx / 192, k = idx % 192; qkvT[idx] = f2bf(qkv_w[k * 576 + n]); return; }
    idx -= 110592;
    if (idx < 36864) { int n = idx / 192, k = idx % 192; projT[idx] = f2bf(proj_w[k * 192 + n]); return; }
    idx -= 36864;
    if (idx < 147456) { int n = idx / 192, k = idx % 192; fc1T[idx] = f2bf(fc1_w[k * 768 + n]); return; }
    idx -= 147456;
    if (idx < 147456) { int n = idx / 768, k = idx % 768; fc2T[idx] = f2bf(fc2_w[k * 192 + n]); return; }
    idx -= 147456;
    if (idx < 14406) {
        int h = idx / 2401; int rest = idx % 2401; int a = rest / 49, b = rest % 49;
        int d = 13 * ((a % 7) - (b % 7) + (a / 7) - (b / 7) + 12);
        if (d > 168) d = 168;
        biasT[idx] = rel_table[d * 6 + h];
        return;
    }
    idx -= 14406;
    if (idx < 153664) {
        int w = idx / 2401; int rest = idx % 2401; int a = rest / 49, b = rest % 49;
        int wy = w / 8, wx = w % 8;
        int ya = wy * 7 + a / 7, xa = wx * 7 + a % 7;
        int yb = wy * 7 + b / 7, xb = wx * 7 + b % 7;
        int lya = ya < 49 ? 0 : (ya < 53 ? 1 : 2);
        int lxa = xa < 49 ? 0 : (xa < 53 ? 1 : 2);
        int lyb = yb < 49 ? 0 : (yb < 53 ? 1 : 2);
        int lxb = xb < 49 ? 0 : (xb < 53 ? 1 : 2);
        maskT[idx] = ((lya * 3 + lxa) != (lyb * 3 + lxb)) ? -100.0f : 0.0f;
        return;
    }
}

// ---------------- attention megakernel ----------------
// 1 block/window, 256 threads (4 waves), m-tile = wave (16 rows, wave-private).
// LDS (static, 48.5 KB -> 3 blocks/CU):
//   xln [64][200] bf16   LN1 rows (pad rows zeroed)     stride 100 dw (== 4 mod 32)
//   qo  [64][40]  bf16   per-head Q; reused as O        stride  20 dw (==20 mod 32)
//   kl  [64][40]  bf16   per-head K
//   vt  [32][72]  bf16   per-head V^T [dim][token]      stride  36 dw (== 4 mod 32)
//   Pl  [64][72]  bf16   softmax probs
__global__ __launch_bounds__(256, 3) void attn_kernel(
    const float* __restrict__ x, const float* __restrict__ n1g, const float* __restrict__ n1b,
    const float* __restrict__ qkv_b, const float* __restrict__ proj_b,
    const ushort_t* __restrict__ qkvT, const ushort_t* __restrict__ projT,
    const float* __restrict__ biasT, const float* __restrict__ maskT,
    float* __restrict__ out) {
    __shared__ ushort_t xln[64 * 200];
    __shared__ ushort_t qo [64 * 40];
    __shared__ ushort_t kl [64 * 40];
    __shared__ ushort_t vt [32 * 72];
    __shared__ ushort_t Pl [64 * 72];

    const int tid = threadIdx.x;
    const int wave = tid >> 6, lane = tid & 63;
    const int ln16 = lane & 15, sub = lane >> 4;
    const int w = blockIdx.x;
    const int batch = w >> 6, wi = w & 63;
    const int wy = wi >> 3, wx = wi & 7;
    const f32x4 zero4 = {0.f, 0.f, 0.f, 0.f};

    // ---- phase 0: gather + LN1, wave-private rows (no barrier needed) ----
    for (int rr = 0; rr < 16; ++rr) {
        int row = wave * 16 + rr;
        if (row < 49) {
            int ty = row / 7, tx = row % 7;
            int y  = wy * 7 + ty + 3; if (y >= 56) y -= 56;
            int xx = wx * 7 + tx + 3; if (xx >= 56) xx -= 56;
            const float* xr = x + (size_t)(batch * 3136 + y * 56 + xx) * CC;
            float v0 = xr[lane], v1 = xr[lane + 64], v2 = xr[lane + 128];
            float s = v0 + v1 + v2;
            #pragma unroll
            for (int m = 32; m; m >>= 1) s += __shfl_xor(s, m);
            float mu = s * (1.0f / 192.0f);
            float d0 = v0 - mu, d1 = v1 - mu, d2 = v2 - mu;
            float q = d0 * d0 + d1 * d1 + d2 * d2;
            #pragma unroll
            for (int m = 32; m; m >>= 1) q += __shfl_xor(q, m);
            float rs = rsqrtf(q * (1.0f / 192.0f) + 1e-5f);
            xln[row * 200 + lane]       = f2bf(d0 * rs * n1g[lane]       + n1b[lane]);
            xln[row * 200 + lane + 64]  = f2bf(d1 * rs * n1g[lane + 64]  + n1b[lane + 64]);
            xln[row * 200 + lane + 128] = f2bf(d2 * rs * n1g[lane + 128] + n1b[lane + 128]);
        } else {
            xln[row * 200 + lane] = 0; xln[row * 200 + lane + 64] = 0; xln[row * 200 + lane + 128] = 0;
        }
    }

    f32x4 accP[12];
    #pragma unroll
    for (int n = 0; n < 12; ++n) accP[n] = zero4;

    const float scale = 0.17677669529663689f;
    const float* bptr0 = biasT;
    const float* mptr  = maskT + wi * 2401;

    for (int h = 0; h < 6; ++h) {
        // ---- QKV for head h: [64,192] x [192,96] ----
        f32x4 acc6[6];
        #pragma unroll
        for (int n = 0; n < 6; ++n) acc6[n] = zero4;
        const int cb0 = h * 32;
        for (int kk = 0; kk < 6; ++kk) {
            short8 a = *(const short8*)(xln + (wave * 16 + ln16) * 200 + kk * 32 + 8 * sub);
            #pragma unroll
            for (int n = 0; n < 6; ++n) {
                int colbase = (n >> 1) * 192 + cb0 + (n & 1) * 16;  // Q,Q,K,K,V,V tiles
                short8 b = *(const short8*)(qkvT + (size_t)(colbase + ln16) * 192 + kk * 32 + 8 * sub);
                acc6[n] = mfma16(a, b, acc6[n]);
            }
        }
        #pragma unroll
        for (int n = 0; n < 6; ++n) {
            int colbase = (n >> 1) * 192 + cb0 + (n & 1) * 16;
            float bv = qkv_b[colbase + ln16];
            int dim = (n & 1) * 16 + ln16;  // local dim 0..31
            #pragma unroll
            for (int r = 0; r < 4; ++r) {
                int row = wave * 16 + 4 * sub + r;
                ushort_t hv = f2bf(acc6[n][r] + bv);
                if (n < 2)      qo[row * 40 + dim] = hv;
                else if (n < 4) kl[row * 40 + dim] = hv;
                else            vt[dim * 72 + row] = hv;
            }
        }
        __syncthreads();  // kl/vt now visible to all waves

        // ---- QK^T (per-wave m-tile) ----
        f32x4 s4[4];
        {
            short8 aq = *(const short8*)(qo + (wave * 16 + ln16) * 40 + 8 * sub);
            #pragma unroll
            for (int n = 0; n < 4; ++n) {
                short8 bk = *(const short8*)(kl + (n * 16 + ln16) * 40 + 8 * sub);
                s4[n] = mfma16(aq, bk, zero4);
            }
        }
        const float* bptr = bptr0 + h * 2401;
        #pragma unroll
        for (int n = 0; n < 4; ++n) {
            int col = n * 16 + ln16;
            #pragma unroll
            for (int r = 0; r < 4; ++r) {
                int row = wave * 16 + 4 * sub + r;
                s4[n][r] = (row < 49 && col < 49)
                    ? s4[n][r] * scale + bptr[row * 49 + col] + mptr[row * 49 + col]
                    : -1e30f;
            }
        }
        // ---- softmax over 64 cols (16-lane groups) ----
        #pragma unroll
        for (int r = 0; r < 4; ++r) {
            float mx = fmaxf(fmaxf(s4[0][r], s4[1][r]), fmaxf(s4[2][r], s4[3][r]));
            mx = fmaxf(mx, __shfl_xor(mx, 1, 16));
            mx = fmaxf(mx, __shfl_xor(mx, 2, 16));
            mx = fmaxf(mx, __shfl_xor(mx, 4, 16));
            mx = fmaxf(mx, __shfl_xor(mx, 8, 16));
            float e0 = __expf(s4[0][r] - mx), e1 = __expf(s4[1][r] - mx);
            float e2 = __expf(s4[2][r] - mx), e3 = __expf(s4[3][r] - mx);
            float sm = e0 + e1 + e2 + e3;
            sm += __shfl_xor(sm, 1, 16);
            sm += __shfl_xor(sm, 2, 16);
            sm += __shfl_xor(sm, 4, 16);
            sm += __shfl_xor(sm, 8, 16);
            float inv = 1.0f / sm;
            int row = wave * 16 + 4 * sub + r;
            Pl[row * 72 +      ln16] = f2bf(e0 * inv);
            Pl[row * 72 + 16 + ln16] = f2bf(e1 * inv);
            Pl[row * 72 + 32 + ln16] = f2bf(e2 * inv);
            Pl[row * 72 + 48 + ln16] = f2bf(e3 * inv);
        }
        // ---- PV (Pl rows wave-private; vt synced) ----
        f32x4 o2[2]; o2[0] = zero4; o2[1] = zero4;
        #pragma unroll
        for (int ks = 0; ks < 2; ++ks) {
            short8 ap = *(const short8*)(Pl + (wave * 16 + ln16) * 72 + ks * 32 + 8 * sub);
            #pragma unroll
            for (int n2 = 0; n2 < 2; ++n2) {
                short8 bv = *(const short8*)(vt + (n2 * 16 + ln16) * 72 + ks * 32 + 8 * sub);
                o2[n2] = mfma16(ap, bv, o2[n2]);
            }
        }
        // ---- O into qo (wave-private rows; Q dead after QK^T) ----
        #pragma unroll
        for (int n2 = 0; n2 < 2; ++n2)
            #pragma unroll
            for (int r = 0; r < 4; ++r) {
                int row = wave * 16 + 4 * sub + r;
                qo[row * 40 + n2 * 16 + ln16] = f2bf(o2[n2][r]);
            }
        // ---- proj partial (k = this head's 32 dims) ----
        {
            short8 ao = *(const short8*)(qo + (wave * 16 + ln16) * 40 + 8 * sub);
            #pragma unroll
            for (int n = 0; n < 12; ++n) {
                short8 bp = *(const short8*)(projT + (size_t)(n * 16 + ln16) * 192 + h * 32 + 8 * sub);
                accP[n] = mfma16(ao, bp, accP[n]);
            }
        }
        __syncthreads();  // protect kl/vt before next head rewrites
    }

    // ---- epilogue: proj bias + residual, scatter ----
    #pragma unroll
    for (int n = 0; n < 12; ++n) {
        int col = n * 16 + ln16;
        float pb = proj_b[col];
        #pragma unroll
        for (int r = 0; r < 4; ++r) {
            int row = wave * 16 + 4 * sub + r;
            if (row < 49) {
                int ty = row / 7, tx = row % 7;
                int y  = wy * 7 + ty + 3; if (y >= 56) y -= 56;
                int xx = wx * 7 + tx + 3; if (xx >= 56) xx -= 56;
                size_t g = (size_t)(batch * 3136 + y * 56 + xx) * CC;
                out[g + col] = accP[n][r] + pb + x[g + col];
            }
        }
    }
}

// ---------------- MLP megakernel ----------------
// 64 tokens/block (1568 blocks), 256 threads, m-tile = wave. Hidden chunked
// by 128 cols; all LDS tiles wave-row-private -> zero barriers.
__global__ __launch_bounds__(256, 3) void mlp_kernel(
    float* __restrict__ out, const float* __restrict__ n2g, const float* __restrict__ n2b,
    const float* __restrict__ fc1_b, const float* __restrict__ fc2_b,
    const ushort_t* __restrict__ fc1T, const ushort_t* __restrict__ fc2T) {
    __shared__ ushort_t aln [64 * 200];
    __shared__ ushort_t hidc[64 * 136];
    const int tid = threadIdx.x;
    const int wave = tid >> 6, lane = tid & 63;
    const int ln16 = lane & 15, sub = lane >> 4;
    const size_t t0 = (size_t)blockIdx.x * 64;
    const f32x4 zero4 = {0.f, 0.f, 0.f, 0.f};

    // LN2 (wave-private rows)
    for (int rr = 0; rr < 16; ++rr) {
        int row = wave * 16 + rr;
        const float* xr = out + (t0 + row) * CC;
        float v0 = xr[lane], v1 = xr[lane + 64], v2 = xr[lane + 128];
        float s = v0 + v1 + v2;
        #pragma unroll
        for (int m = 32; m; m >>= 1) s += __shfl_xor(s, m);
        float mu = s * (1.0f / 192.0f);
        float d0 = v0 - mu, d1 = v1 - mu, d2 = v2 - mu;
        float q = d0 * d0 + d1 * d1 + d2 * d2;
        #pragma unroll
        for (int m = 32; m; m >>= 1) q += __shfl_xor(q, m);
        float rs = rsqrtf(q * (1.0f / 192.0f) + 1e-5f);
        aln[row * 200 + lane]       = f2bf(d0 * rs * n2g[lane]       + n2b[lane]);
        aln[row * 200 + lane + 64]  = f2bf(d1 * rs * n2g[lane + 64]  + n2b[lane + 64]);
        aln[row * 200 + lane + 128] = f2bf(d2 * rs * n2g[lane + 128] + n2b[lane + 128]);
    }

    f32x4 accO[12];
    #pragma unroll
    for (int n = 0; n < 12; ++n) accO[n] = zero4;

    for (int c = 0; c < 6; ++c) {
        // FC1 chunk: [64,192] x [192,128]
        f32x4 acc1[8];
        #pragma unroll
        for (int n = 0; n < 8; ++n) acc1[n] = zero4;
        for (int kk = 0; kk < 6; ++kk) {
            short8 a = *(const short8*)(aln + (wave * 16 + ln16) * 200 + kk * 32 + 8 * sub);
            #pragma unroll
            for (int n = 0; n < 8; ++n) {
                short8 b = *(const short8*)(fc1T + (size_t)(c * 128 + n * 16 + ln16) * 192 + kk * 32 + 8 * sub);
                acc1[n] = mfma16(a, b, acc1[n]);
            }
        }
        #pragma unroll
        for (int n = 0; n < 8; ++n) {
            float fb = fc1_b[c * 128 + n * 16 + ln16];
            #pragma unroll
            for (int r = 0; r < 4; ++r) {
                int row = wave * 16 + 4 * sub + r;
                float hv = acc1[n][r] + fb;
                float ge = 0.5f * hv * (1.0f + erff(hv * 0.70710678118654752f));
                hidc[row * 136 + n * 16 + ln16] = f2bf(ge);
            }
        }
        // FC2 partial: [64,128] x [128,192], accumulate
        #pragma unroll
        for (int kk = 0; kk < 4; ++kk) {
            short8 a = *(const short8*)(hidc + (wave * 16 + ln16) * 136 + kk * 32 + 8 * sub);
            #pragma unroll
            for (int n = 0; n < 12; ++n) {
                short8 b = *(const short8*)(fc2T + (size_t)(n * 16 + ln16) * 768 + c * 128 + kk * 32 + 8 * sub);
                accO[n] = mfma16(a, b, accO[n]);
            }
        }
    }

    #pragma unroll
    for (int n = 0; n < 12; ++n) {
        int col = n * 16 + ln16;
        float fb = fc2_b[col];
        #pragma unroll
        for (int r = 0; r < 4; ++r) {
            int row = wave * 16 + 4 * sub + r;
            size_t o = (t0 + row) * CC + col;
            out[o] = accO[n][r] + fb + out[o];
        }
    }
}

// ---------------- launch ----------------
extern "C" void kernel_launch(void* const* d_in, const int* in_sizes, int n_in,
                              void* d_out, int out_size, void* d_ws, size_t ws_size,
                              hipStream_t stream) {
    const float* x      = (const float*)d_in[0];
    const float* n1g    = (const float*)d_in[1];
    const float* n1b    = (const float*)d_in[2];
    const float* qkv_w  = (const float*)d_in[3];
    const float* qkv_b  = (const float*)d_in[4];
    const float* rel_t  = (const float*)d_in[5];
    const float* proj_w = (const float*)d_in[6];
    const float* proj_b = (const float*)d_in[7];
    const float* n2g    = (const float*)d_in[8];
    const float* n2b    = (const float*)d_in[9];
    const float* fc1_w  = (const float*)d_in[10];
    const float* fc1_b  = (const float*)d_in[11];
    const float* fc2_w  = (const float*)d_in[12];
    const float* fc2_b  = (const float*)d_in[13];
    float* out = (float*)d_out;

    char* ws = (char*)d_ws;
    ushort_t* qkvT  = (ushort_t*)(ws + OFF_QKVT);
    ushort_t* projT = (ushort_t*)(ws + OFF_PROJT);
    ushort_t* fc1T  = (ushort_t*)(ws + OFF_FC1T);
    ushort_t* fc2T  = (ushort_t*)(ws + OFF_FC2T);
    float* biasT    = (float*)(ws + OFF_BIAS);
    float* maskT    = (float*)(ws + OFF_MASK);

    int prep_blocks = (PREP_TOTAL + 255) / 256;
    prep_kernel<<<prep_blocks, 256, 0, stream>>>(qkv_w, proj_w, fc1_w, fc2_w, rel_t,
                                                 qkvT, projT, fc1T, fc2T, biasT, maskT);

    attn_kernel<<<2048, 256, 0, stream>>>(x, n1g, n1b, qkv_b, proj_b,
                                          qkvT, projT, biasT, maskT, out);

    mlp_kernel<<<1568, 256, 0, stream>>>(out, n2g, n2b, fc1_b, fc2_b, fc1T, fc2T);
}

// Round 3
// 736.602 us; speedup vs baseline: 1.3609x; 1.3070x over previous
//
#include <hip/hip_runtime.h>
#include <hip/hip_bf16.h>

// Swin block, round 3.
//  - lnqkv: LN1 + QKV GEMM over all tokens (n-split waves, m_rep=4),
//    writes qg (scaled, bf16), kg (bf16), vtw ([win][dim][tok] bf16).
//  - attnwin: per-window attention, barrier-free, frags direct from global,
//    fused bias+mask table, proj accumulated per head.
//  - mlp3: n-split waves, m_rep=4, unique B-loads per block.
//  - fallback: round-2 monolithic attn if ws too small.

using f32x4  = __attribute__((ext_vector_type(4))) float;
using short8 = __attribute__((ext_vector_type(8))) short;
typedef unsigned short ushort_t;

__device__ __forceinline__ ushort_t f2bf(float f) {
    __hip_bfloat16 h = __float2bfloat16(f);
    return __builtin_bit_cast(ushort_t, h);
}
__device__ __forceinline__ f32x4 mfma16(short8 a, short8 b, f32x4 c) {
    return __builtin_amdgcn_mfma_f32_16x16x32_bf16(a, b, c, 0, 0, 0);
}

#define CC 192

// ws offsets (bytes)
#define OFF_QKVT   0          // [576][192] bf16
#define OFF_PROJT  221184     // [192][192] bf16
#define OFF_FC1T   294912     // [768][192] bf16
#define OFF_FC2T   589824     // [192][768] bf16
#define OFF_BIAS   884736     // [6][49][49] f32
#define OFF_MASK   942592     // [64][49][49] f32
#define OFF_BM     1557504    // [64][6][49][49] f32 fused bias+mask
#define OFF_QG     5245440    // [100352][192] bf16 (scaled Q)
#define OFF_KG     43780608   // [100352][192] bf16
#define OFF_VT     82315776   // [2048][192][64] bf16
#define WS_NEED    132647424
#define PREP_SMALL 610438
#define PREP_BIG   1532422

// ---------------- prep ----------------
__global__ void prep_kernel(const float* __restrict__ qkv_w, const float* __restrict__ proj_w,
                            const float* __restrict__ fc1_w, const float* __restrict__ fc2_w,
                            const float* __restrict__ rel_table,
                            ushort_t* __restrict__ qkvT, ushort_t* __restrict__ projT,
                            ushort_t* __restrict__ fc1T, ushort_t* __restrict__ fc2T,
                            float* __restrict__ biasT, float* __restrict__ maskT,
                            float* __restrict__ bm, int full) {
    int idx = blockIdx.x * 256 + threadIdx.x;
    if (idx < 110592) { int n = idx / 192, k = idx % 192; qkvT[idx] = f2bf(qkv_w[k * 576 + n]); return; }
    idx -= 110592;
    if (idx < 36864) { int n = idx / 192, k = idx % 192; projT[idx] = f2bf(proj_w[k * 192 + n]); return; }
    idx -= 36864;
    if (idx < 147456) { int n = idx / 192, k = idx % 192; fc1T[idx] = f2bf(fc1_w[k * 768 + n]); return; }
    idx -= 147456;
    if (idx < 147456) { int n = idx / 768, k = idx % 768; fc2T[idx] = f2bf(fc2_w[k * 192 + n]); return; }
    idx -= 147456;
    if (idx < 14406) {
        int h = idx / 2401; int rest = idx % 2401; int a = rest / 49, b = rest % 49;
        int d = 13 * ((a % 7) - (b % 7) + (a / 7) - (b / 7) + 12);
        if (d > 168) d = 168;
        biasT[idx] = rel_table[d * 6 + h];
        return;
    }
    idx -= 14406;
    if (idx < 153664) {
        int w = idx / 2401; int rest = idx % 2401; int a = rest / 49, b = rest % 49;
        int wy = w / 8, wx = w % 8;
        int ya = wy * 7 + a / 7, xa = wx * 7 + a % 7;
        int yb = wy * 7 + b / 7, xb = wx * 7 + b % 7;
        int lya = ya < 49 ? 0 : (ya < 53 ? 1 : 2);
        int lxa = xa < 49 ? 0 : (xa < 53 ? 1 : 2);
        int lyb = yb < 49 ? 0 : (yb < 53 ? 1 : 2);
        int lxb = xb < 49 ? 0 : (xb < 53 ? 1 : 2);
        maskT[idx] = ((lya * 3 + lxa) != (lyb * 3 + lxb)) ? -100.0f : 0.0f;
        return;
    }
    idx -= 153664;
    if (full && idx < 921984) {  // bm[wi][h][a][b] = bias + mask
        int wi = idx / 14406; int r2 = idx % 14406;
        int h = r2 / 2401; int r3 = r2 % 2401;
        int a = r3 / 49, b = r3 % 49;
        int d = 13 * ((a % 7) - (b % 7) + (a / 7) - (b / 7) + 12);
        if (d > 168) d = 168;
        float bias = rel_table[d * 6 + h];
        int wy = wi / 8, wx = wi % 8;
        int ya = wy * 7 + a / 7, xa = wx * 7 + a % 7;
        int yb = wy * 7 + b / 7, xb = wx * 7 + b % 7;
        int lya = ya < 49 ? 0 : (ya < 53 ? 1 : 2);
        int lxa = xa < 49 ? 0 : (xa < 53 ? 1 : 2);
        int lyb = yb < 49 ? 0 : (yb < 53 ? 1 : 2);
        int lxb = xb < 49 ? 0 : (xb < 53 ? 1 : 2);
        float mask = ((lya * 3 + lxa) != (lyb * 3 + lxb)) ? -100.0f : 0.0f;
        bm[idx] = bias + mask;
        return;
    }
}

// ---------------- phase A: LN1 + QKV GEMM ----------------
// 64 tokens/block (1568 blocks), 4 waves, n-split (9 n-tiles/wave), m_rep=4.
__global__ __launch_bounds__(256, 3) void lnqkv_kernel(
    const float* __restrict__ x, const float* __restrict__ n1g, const float* __restrict__ n1b,
    const ushort_t* __restrict__ qkvT, const float* __restrict__ qkv_b,
    ushort_t* __restrict__ qg, ushort_t* __restrict__ kg, ushort_t* __restrict__ vtw) {
    __shared__ ushort_t xln[64 * 200];
    const int tid = threadIdx.x;
    const int wave = tid >> 6, lane = tid & 63;
    const int ln16 = lane & 15, sub = lane >> 4;
    const int t0 = blockIdx.x * 64;
    const f32x4 zero4 = {0.f, 0.f, 0.f, 0.f};

    for (int rr = 0; rr < 16; ++rr) {
        int row = wave * 16 + rr;
        const float* xr = x + (size_t)(t0 + row) * CC;
        float v0 = xr[lane], v1 = xr[lane + 64], v2 = xr[lane + 128];
        float s = v0 + v1 + v2;
        #pragma unroll
        for (int m = 32; m; m >>= 1) s += __shfl_xor(s, m);
        float mu = s * (1.0f / 192.0f);
        float d0 = v0 - mu, d1 = v1 - mu, d2 = v2 - mu;
        float q = d0 * d0 + d1 * d1 + d2 * d2;
        #pragma unroll
        for (int m = 32; m; m >>= 1) q += __shfl_xor(q, m);
        float rs = rsqrtf(q * (1.0f / 192.0f) + 1e-5f);
        xln[row * 200 + lane]       = f2bf(d0 * rs * n1g[lane]       + n1b[lane]);
        xln[row * 200 + lane + 64]  = f2bf(d1 * rs * n1g[lane + 64]  + n1b[lane + 64]);
        xln[row * 200 + lane + 128] = f2bf(d2 * rs * n1g[lane + 128] + n1b[lane + 128]);
    }
    __syncthreads();

    for (int g = 0; g < 3; ++g) {
        f32x4 acc[4][3];
        #pragma unroll
        for (int m = 0; m < 4; ++m)
            #pragma unroll
            for (int n = 0; n < 3; ++n) acc[m][n] = zero4;
        const int tbase = wave * 9 + g * 3;
        for (int kk = 0; kk < 6; ++kk) {
            short8 a[4];
            #pragma unroll
            for (int m = 0; m < 4; ++m)
                a[m] = *(const short8*)(xln + (m * 16 + ln16) * 200 + kk * 32 + 8 * sub);
            #pragma unroll
            for (int n = 0; n < 3; ++n) {
                short8 b = *(const short8*)(qkvT + (size_t)((tbase + n) * 16 + ln16) * 192 + kk * 32 + 8 * sub);
                #pragma unroll
                for (int m = 0; m < 4; ++m) acc[m][n] = mfma16(a[m], b, acc[m][n]);
            }
        }
        #pragma unroll
        for (int n = 0; n < 3; ++n) {
            int col = (tbase + n) * 16 + ln16;
            float bv = qkv_b[col];
            #pragma unroll
            for (int m = 0; m < 4; ++m)
                #pragma unroll
                for (int r = 0; r < 4; ++r) {
                    int tok = t0 + m * 16 + 4 * sub + r;
                    float val = acc[m][n][r] + bv;
                    if (col < 192) {
                        qg[(size_t)tok * 192 + col] = f2bf(val * 0.17677669529663689f);
                    } else if (col < 384) {
                        kg[(size_t)tok * 192 + col - 192] = f2bf(val);
                    } else {
                        int c = col - 384;
                        int bb = tok / 3136, yx = tok % 3136;
                        int y = yx / 56, xx = yx % 56;
                        int ys = y + 53;  if (ys >= 56) ys -= 56;
                        int xs = xx + 53; if (xs >= 56) xs -= 56;
                        int win = bb * 64 + (ys / 7) * 8 + (xs / 7);
                        int tw  = (ys % 7) * 7 + (xs % 7);
                        vtw[(size_t)win * 12288 + c * 64 + tw] = f2bf(val);
                    }
                }
        }
    }
}

// ---------------- phase B: windowed attention ----------------
// 1 block/window (2048), 4 waves, wave = 16 rows x all heads. Zero barriers.
// LDS: P[4][16][72] + O[4][16][72] = 18.4 KB.
__global__ __launch_bounds__(256, 3) void attnwin_kernel(
    const float* __restrict__ x, const float* __restrict__ proj_b,
    const ushort_t* __restrict__ qg, const ushort_t* __restrict__ kg,
    const ushort_t* __restrict__ vtw, const ushort_t* __restrict__ projT,
    const float* __restrict__ bm, float* __restrict__ out) {
    __shared__ ushort_t Pl[4][16 * 72];
    __shared__ ushort_t oL[4][16 * 72];
    const int tid = threadIdx.x;
    const int wave = tid >> 6, lane = tid & 63;
    const int ln16 = lane & 15, sub = lane >> 4;
    const int win = blockIdx.x;
    const int b = win >> 6, wi = win & 63;
    const int wy = wi >> 3, wx = wi & 7;
    const f32x4 zero4 = {0.f, 0.f, 0.f, 0.f};

    // A-frag token (this wave's row = ln16), clamped for pad rows
    size_t tokA;
    {
        int j = wave * 16 + ln16; if (j > 48) j = 48;
        int y  = wy * 7 + j / 7 + 3; if (y >= 56) y -= 56;
        int xx = wx * 7 + j % 7 + 3; if (xx >= 56) xx -= 56;
        tokA = (size_t)(b * 3136 + y * 56 + xx);
    }
    // B-frag key tokens (col = n*16+ln16), clamped
    size_t tokB[4];
    #pragma unroll
    for (int n = 0; n < 4; ++n) {
        int j = n * 16 + ln16; if (j > 48) j = 48;
        int y  = wy * 7 + j / 7 + 3; if (y >= 56) y -= 56;
        int xx = wx * 7 + j % 7 + 3; if (xx >= 56) xx -= 56;
        tokB[n] = (size_t)(b * 3136 + y * 56 + xx);
    }

    f32x4 accP[12];
    #pragma unroll
    for (int n = 0; n < 12; ++n) accP[n] = zero4;

    ushort_t* Pw = Pl[wave];
    ushort_t* Ow = oL[wave];

    for (int h = 0; h < 6; ++h) {
        // ---- S = QK^T (scale pre-folded into qg) ----
        short8 qf = *(const short8*)(qg + tokA * 192 + h * 32 + 8 * sub);
        f32x4 s4[4];
        #pragma unroll
        for (int n = 0; n < 4; ++n) {
            short8 kf = *(const short8*)(kg + tokB[n] * 192 + h * 32 + 8 * sub);
            s4[n] = mfma16(qf, kf, zero4);
        }
        // ---- + fused bias+mask ----
        const float* bmh = bm + (size_t)(wi * 6 + h) * 2401;
        #pragma unroll
        for (int n = 0; n < 4; ++n) {
            int col = n * 16 + ln16;
            #pragma unroll
            for (int r = 0; r < 4; ++r) {
                int row = wave * 16 + 4 * sub + r;
                s4[n][r] = (row < 49 && col < 49) ? s4[n][r] + bmh[row * 49 + col] : -1e30f;
            }
        }
        // ---- softmax (per row, 16-lane groups) ----
        #pragma unroll
        for (int r = 0; r < 4; ++r) {
            float mx = fmaxf(fmaxf(s4[0][r], s4[1][r]), fmaxf(s4[2][r], s4[3][r]));
            mx = fmaxf(mx, __shfl_xor(mx, 1, 16));
            mx = fmaxf(mx, __shfl_xor(mx, 2, 16));
            mx = fmaxf(mx, __shfl_xor(mx, 4, 16));
            mx = fmaxf(mx, __shfl_xor(mx, 8, 16));
            float e0 = __expf(s4[0][r] - mx), e1 = __expf(s4[1][r] - mx);
            float e2 = __expf(s4[2][r] - mx), e3 = __expf(s4[3][r] - mx);
            float sm = e0 + e1 + e2 + e3;
            sm += __shfl_xor(sm, 1, 16);
            sm += __shfl_xor(sm, 2, 16);
            sm += __shfl_xor(sm, 4, 16);
            sm += __shfl_xor(sm, 8, 16);
            float inv = 1.0f / sm;
            int rl = 4 * sub + r;
            Pw[rl * 72 +      ln16] = f2bf(e0 * inv);
            Pw[rl * 72 + 16 + ln16] = f2bf(e1 * inv);
            Pw[rl * 72 + 32 + ln16] = f2bf(e2 * inv);
            Pw[rl * 72 + 48 + ln16] = f2bf(e3 * inv);
        }
        // ---- PV: P (own LDS region) x V^T (global, contiguous) ----
        f32x4 o2[2]; o2[0] = zero4; o2[1] = zero4;
        #pragma unroll
        for (int kk = 0; kk < 2; ++kk) {
            short8 ap = *(const short8*)(Pw + ln16 * 72 + kk * 32 + 8 * sub);
            #pragma unroll
            for (int n2 = 0; n2 < 2; ++n2) {
                short8 bv = *(const short8*)(vtw + (size_t)win * 12288
                                             + (h * 32 + n2 * 16 + ln16) * 64 + kk * 32 + 8 * sub);
                o2[n2] = mfma16(ap, bv, o2[n2]);
            }
        }
        // ---- O -> own LDS region ----
        #pragma unroll
        for (int n2 = 0; n2 < 2; ++n2)
            #pragma unroll
            for (int r = 0; r < 4; ++r)
                Ow[(4 * sub + r) * 72 + n2 * 16 + ln16] = f2bf(o2[n2][r]);
        // ---- proj partial accumulate (k-slice = this head's 32 dims) ----
        {
            short8 ao = *(const short8*)(Ow + ln16 * 72 + 8 * sub);
            #pragma unroll
            for (int n = 0; n < 12; ++n) {
                short8 bp = *(const short8*)(projT + (size_t)(n * 16 + ln16) * 192 + h * 32 + 8 * sub);
                accP[n] = mfma16(ao, bp, accP[n]);
            }
        }
    }

    // ---- epilogue: + proj bias + residual, scatter ----
    #pragma unroll
    for (int n = 0; n < 12; ++n) {
        int col = n * 16 + ln16;
        float pb = proj_b[col];
        #pragma unroll
        for (int r = 0; r < 4; ++r) {
            int row = wave * 16 + 4 * sub + r;
            if (row < 49) {
                int y  = wy * 7 + row / 7 + 3; if (y >= 56) y -= 56;
                int xx = wx * 7 + row % 7 + 3; if (xx >= 56) xx -= 56;
                size_t g = (size_t)(b * 3136 + y * 56 + xx) * CC;
                out[g + col] = accP[n][r] + pb + x[g + col];
            }
        }
    }
}

// ---------------- fallback: round-2 monolithic attention ----------------
__global__ __launch_bounds__(256, 3) void attn_kernel(
    const float* __restrict__ x, const float* __restrict__ n1g, const float* __restrict__ n1b,
    const float* __restrict__ qkv_b, const float* __restrict__ proj_b,
    const ushort_t* __restrict__ qkvT, const ushort_t* __restrict__ projT,
    const float* __restrict__ biasT, const float* __restrict__ maskT,
    float* __restrict__ out) {
    __shared__ ushort_t xln[64 * 200];
    __shared__ ushort_t qo [64 * 40];
    __shared__ ushort_t kl [64 * 40];
    __shared__ ushort_t vt [32 * 72];
    __shared__ ushort_t Pl [64 * 72];
    const int tid = threadIdx.x;
    const int wave = tid >> 6, lane = tid & 63;
    const int ln16 = lane & 15, sub = lane >> 4;
    const int w = blockIdx.x;
    const int batch = w >> 6, wi = w & 63;
    const int wy = wi >> 3, wx = wi & 7;
    const f32x4 zero4 = {0.f, 0.f, 0.f, 0.f};

    for (int rr = 0; rr < 16; ++rr) {
        int row = wave * 16 + rr;
        if (row < 49) {
            int ty = row / 7, tx = row % 7;
            int y  = wy * 7 + ty + 3; if (y >= 56) y -= 56;
            int xx = wx * 7 + tx + 3; if (xx >= 56) xx -= 56;
            const float* xr = x + (size_t)(batch * 3136 + y * 56 + xx) * CC;
            float v0 = xr[lane], v1 = xr[lane + 64], v2 = xr[lane + 128];
            float s = v0 + v1 + v2;
            #pragma unroll
            for (int m = 32; m; m >>= 1) s += __shfl_xor(s, m);
            float mu = s * (1.0f / 192.0f);
            float d0 = v0 - mu, d1 = v1 - mu, d2 = v2 - mu;
            float q = d0 * d0 + d1 * d1 + d2 * d2;
            #pragma unroll
            for (int m = 32; m; m >>= 1) q += __shfl_xor(q, m);
            float rs = rsqrtf(q * (1.0f / 192.0f) + 1e-5f);
            xln[row * 200 + lane]       = f2bf(d0 * rs * n1g[lane]       + n1b[lane]);
            xln[row * 200 + lane + 64]  = f2bf(d1 * rs * n1g[lane + 64]  + n1b[lane + 64]);
            xln[row * 200 + lane + 128] = f2bf(d2 * rs * n1g[lane + 128] + n1b[lane + 128]);
        } else {
            xln[row * 200 + lane] = 0; xln[row * 200 + lane + 64] = 0; xln[row * 200 + lane + 128] = 0;
        }
    }

    f32x4 accP[12];
    #pragma unroll
    for (int n = 0; n < 12; ++n) accP[n] = zero4;
    const float scale = 0.17677669529663689f;
    const float* mptr = maskT + wi * 2401;

    for (int h = 0; h < 6; ++h) {
        f32x4 acc6[6];
        #pragma unroll
        for (int n = 0; n < 6; ++n) acc6[n] = zero4;
        const int cb0 = h * 32;
        for (int kk = 0; kk < 6; ++kk) {
            short8 a = *(const short8*)(xln + (wave * 16 + ln16) * 200 + kk * 32 + 8 * sub);
            #pragma unroll
            for (int n = 0; n < 6; ++n) {
                int colbase = (n >> 1) * 192 + cb0 + (n & 1) * 16;
                short8 b = *(const short8*)(qkvT + (size_t)(colbase + ln16) * 192 + kk * 32 + 8 * sub);
                acc6[n] = mfma16(a, b, acc6[n]);
            }
        }
        #pragma unroll
        for (int n = 0; n < 6; ++n) {
            int colbase = (n >> 1) * 192 + cb0 + (n & 1) * 16;
            float bv = qkv_b[colbase + ln16];
            int dim = (n & 1) * 16 + ln16;
            #pragma unroll
            for (int r = 0; r < 4; ++r) {
                int row = wave * 16 + 4 * sub + r;
                ushort_t hv = f2bf(acc6[n][r] + bv);
                if (n < 2)      qo[row * 40 + dim] = hv;
                else if (n < 4) kl[row * 40 + dim] = hv;
                else            vt[dim * 72 + row] = hv;
            }
        }
        __syncthreads();

        f32x4 s4[4];
        {
            short8 aq = *(const short8*)(qo + (wave * 16 + ln16) * 40 + 8 * sub);
            #pragma unroll
            for (int n = 0; n < 4; ++n) {
                short8 bk = *(const short8*)(kl + (n * 16 + ln16) * 40 + 8 * sub);
                s4[n] = mfma16(aq, bk, zero4);
            }
        }
        const float* bptr = biasT + h * 2401;
        #pragma unroll
        for (int n = 0; n < 4; ++n) {
            int col = n * 16 + ln16;
            #pragma unroll
            for (int r = 0; r < 4; ++r) {
                int row = wave * 16 + 4 * sub + r;
                s4[n][r] = (row < 49 && col < 49)
                    ? s4[n][r] * scale + bptr[row * 49 + col] + mptr[row * 49 + col]
                    : -1e30f;
            }
        }
        #pragma unroll
        for (int r = 0; r < 4; ++r) {
            float mx = fmaxf(fmaxf(s4[0][r], s4[1][r]), fmaxf(s4[2][r], s4[3][r]));
            mx = fmaxf(mx, __shfl_xor(mx, 1, 16));
            mx = fmaxf(mx, __shfl_xor(mx, 2, 16));
            mx = fmaxf(mx, __shfl_xor(mx, 4, 16));
            mx = fmaxf(mx, __shfl_xor(mx, 8, 16));
            float e0 = __expf(s4[0][r] - mx), e1 = __expf(s4[1][r] - mx);
            float e2 = __expf(s4[2][r] - mx), e3 = __expf(s4[3][r] - mx);
            float sm = e0 + e1 + e2 + e3;
            sm += __shfl_xor(sm, 1, 16);
            sm += __shfl_xor(sm, 2, 16);
            sm += __shfl_xor(sm, 4, 16);
            sm += __shfl_xor(sm, 8, 16);
            float inv = 1.0f / sm;
            int row = wave * 16 + 4 * sub + r;
            Pl[row * 72 +      ln16] = f2bf(e0 * inv);
            Pl[row * 72 + 16 + ln16] = f2bf(e1 * inv);
            Pl[row * 72 + 32 + ln16] = f2bf(e2 * inv);
            Pl[row * 72 + 48 + ln16] = f2bf(e3 * inv);
        }
        f32x4 o2[2]; o2[0] = zero4; o2[1] = zero4;
        #pragma unroll
        for (int ks = 0; ks < 2; ++ks) {
            short8 ap = *(const short8*)(Pl + (wave * 16 + ln16) * 72 + ks * 32 + 8 * sub);
            #pragma unroll
            for (int n2 = 0; n2 < 2; ++n2) {
                short8 bv = *(const short8*)(vt + (n2 * 16 + ln16) * 72 + ks * 32 + 8 * sub);
                o2[n2] = mfma16(ap, bv, o2[n2]);
            }
        }
        #pragma unroll
        for (int n2 = 0; n2 < 2; ++n2)
            #pragma unroll
            for (int r = 0; r < 4; ++r) {
                int row = wave * 16 + 4 * sub + r;
                qo[row * 40 + n2 * 16 + ln16] = f2bf(o2[n2][r]);
            }
        {
            short8 ao = *(const short8*)(qo + (wave * 16 + ln16) * 40 + 8 * sub);
            #pragma unroll
            for (int n = 0; n < 12; ++n) {
                short8 bp = *(const short8*)(projT + (size_t)(n * 16 + ln16) * 192 + h * 32 + 8 * sub);
                accP[n] = mfma16(ao, bp, accP[n]);
            }
        }
        __syncthreads();
    }

    #pragma unroll
    for (int n = 0; n < 12; ++n) {
        int col = n * 16 + ln16;
        float pb = proj_b[col];
        #pragma unroll
        for (int r = 0; r < 4; ++r) {
            int row = wave * 16 + 4 * sub + r;
            if (row < 49) {
                int ty = row / 7, tx = row % 7;
                int y  = wy * 7 + ty + 3; if (y >= 56) y -= 56;
                int xx = wx * 7 + tx + 3; if (xx >= 56) xx -= 56;
                size_t g = (size_t)(batch * 3136 + y * 56 + xx) * CC;
                out[g + col] = accP[n][r] + pb + x[g + col];
            }
        }
    }
}

// ---------------- MLP v3: n-split waves, m_rep=4 ----------------
// 64 tokens/block (1568 blocks). FC1 chunked by 128 hidden cols.
__global__ __launch_bounds__(256, 3) void mlp3_kernel(
    float* __restrict__ out, const float* __restrict__ n2g, const float* __restrict__ n2b,
    const float* __restrict__ fc1_b, const float* __restrict__ fc2_b,
    const ushort_t* __restrict__ fc1T, const ushort_t* __restrict__ fc2T) {
    __shared__ ushort_t aln [64 * 200];
    __shared__ ushort_t hidc[64 * 136];
    const int tid = threadIdx.x;
    const int wave = tid >> 6, lane = tid & 63;
    const int ln16 = lane & 15, sub = lane >> 4;
    const size_t t0 = (size_t)blockIdx.x * 64;
    const f32x4 zero4 = {0.f, 0.f, 0.f, 0.f};

    for (int rr = 0; rr < 16; ++rr) {
        int row = wave * 16 + rr;
        const float* xr = out + (t0 + row) * CC;
        float v0 = xr[lane], v1 = xr[lane + 64], v2 = xr[lane + 128];
        float s = v0 + v1 + v2;
        #pragma unroll
        for (int m = 32; m; m >>= 1) s += __shfl_xor(s, m);
        float mu = s * (1.0f / 192.0f);
        float d0 = v0 - mu, d1 = v1 - mu, d2 = v2 - mu;
        float q = d0 * d0 + d1 * d1 + d2 * d2;
        #pragma unroll
        for (int m = 32; m; m >>= 1) q += __shfl_xor(q, m);
        float rs = rsqrtf(q * (1.0f / 192.0f) + 1e-5f);
        aln[row * 200 + lane]       = f2bf(d0 * rs * n2g[lane]       + n2b[lane]);
        aln[row * 200 + lane + 64]  = f2bf(d1 * rs * n2g[lane + 64]  + n2b[lane + 64]);
        aln[row * 200 + lane + 128] = f2bf(d2 * rs * n2g[lane + 128] + n2b[lane + 128]);
    }
    __syncthreads();

    f32x4 accO[4][3];
    #pragma unroll
    for (int m = 0; m < 4; ++m)
        #pragma unroll
        for (int n = 0; n < 3; ++n) accO[m][n] = zero4;

    for (int c = 0; c < 6; ++c) {
        // FC1: wave's 2 n-tiles (32 cols of this 128-col chunk), all 64 rows
        f32x4 acc1[4][2];
        #pragma unroll
        for (int m = 0; m < 4; ++m)
            #pragma unroll
            for (int n = 0; n < 2; ++n) acc1[m][n] = zero4;
        for (int kk = 0; kk < 6; ++kk) {
            short8 a[4];
            #pragma unroll
            for (int m = 0; m < 4; ++m)
                a[m] = *(const short8*)(aln + (m * 16 + ln16) * 200 + kk * 32 + 8 * sub);
            #pragma unroll
            for (int n = 0; n < 2; ++n) {
                short8 b = *(const short8*)(fc1T + (size_t)(c * 128 + wave * 32 + n * 16 + ln16) * 192 + kk * 32 + 8 * sub);
                #pragma unroll
                for (int m = 0; m < 4; ++m) acc1[m][n] = mfma16(a[m], b, acc1[m][n]);
            }
        }
        #pragma unroll
        for (int n = 0; n < 2; ++n) {
            int cl = wave * 32 + n * 16 + ln16;
            float fb = fc1_b[c * 128 + cl];
            #pragma unroll
            for (int m = 0; m < 4; ++m)
                #pragma unroll
                for (int r = 0; r < 4; ++r) {
                    float hv = acc1[m][n][r] + fb;
                    float ge = 0.5f * hv * (1.0f + erff(hv * 0.70710678118654752f));
                    hidc[(m * 16 + 4 * sub + r) * 136 + cl] = f2bf(ge);
                }
        }
        __syncthreads();
        // FC2 partial: wave's 3 n-tiles (48 out cols), k = this chunk's 128
        #pragma unroll
        for (int kk = 0; kk < 4; ++kk) {
            short8 a[4];
            #pragma unroll
            for (int m = 0; m < 4; ++m)
                a[m] = *(const short8*)(hidc + (m * 16 + ln16) * 136 + kk * 32 + 8 * sub);
            #pragma unroll
            for (int n = 0; n < 3; ++n) {
                short8 b = *(const short8*)(fc2T + (size_t)(wave * 48 + n * 16 + ln16) * 768 + c * 128 + kk * 32 + 8 * sub);
                #pragma unroll
                for (int m = 0; m < 4; ++m) accO[m][n] = mfma16(a[m], b, accO[m][n]);
            }
        }
        __syncthreads();  // WAR on hidc before next chunk
    }

    #pragma unroll
    for (int n = 0; n < 3; ++n) {
        int col = wave * 48 + n * 16 + ln16;
        float fb = fc2_b[col];
        #pragma unroll
        for (int m = 0; m < 4; ++m)
            #pragma unroll
            for (int r = 0; r < 4; ++r) {
                size_t o = (t0 + m * 16 + 4 * sub + r) * CC + col;
                out[o] = accO[m][n][r] + fb + out[o];
            }
    }
}

// ---------------- launch ----------------
extern "C" void kernel_launch(void* const* d_in, const int* in_sizes, int n_in,
                              void* d_out, int out_size, void* d_ws, size_t ws_size,
                              hipStream_t stream) {
    const float* x      = (const float*)d_in[0];
    const float* n1g    = (const float*)d_in[1];
    const float* n1b    = (const float*)d_in[2];
    const float* qkv_w  = (const float*)d_in[3];
    const float* qkv_b  = (const float*)d_in[4];
    const float* rel_t  = (const float*)d_in[5];
    const float* proj_w = (const float*)d_in[6];
    const float* proj_b = (const float*)d_in[7];
    const float* n2g    = (const float*)d_in[8];
    const float* n2b    = (const float*)d_in[9];
    const float* fc1_w  = (const float*)d_in[10];
    const float* fc1_b  = (const float*)d_in[11];
    const float* fc2_w  = (const float*)d_in[12];
    const float* fc2_b  = (const float*)d_in[13];
    float* out = (float*)d_out;

    char* ws = (char*)d_ws;
    ushort_t* qkvT  = (ushort_t*)(ws + OFF_QKVT);
    ushort_t* projT = (ushort_t*)(ws + OFF_PROJT);
    ushort_t* fc1T  = (ushort_t*)(ws + OFF_FC1T);
    ushort_t* fc2T  = (ushort_t*)(ws + OFF_FC2T);
    float* biasT    = (float*)(ws + OFF_BIAS);
    float* maskT    = (float*)(ws + OFF_MASK);
    float* bm       = (float*)(ws + OFF_BM);
    ushort_t* qg    = (ushort_t*)(ws + OFF_QG);
    ushort_t* kg    = (ushort_t*)(ws + OFF_KG);
    ushort_t* vtw   = (ushort_t*)(ws + OFF_VT);

    const int big = ws_size >= (size_t)WS_NEED;
    const int prep_total = big ? PREP_BIG : PREP_SMALL;
    prep_kernel<<<(prep_total + 255) / 256, 256, 0, stream>>>(
        qkv_w, proj_w, fc1_w, fc2_w, rel_t, qkvT, projT, fc1T, fc2T, biasT, maskT, bm, big);

    if (big) {
        lnqkv_kernel<<<1568, 256, 0, stream>>>(x, n1g, n1b, qkvT, qkv_b, qg, kg, vtw);
        attnwin_kernel<<<2048, 256, 0, stream>>>(x, proj_b, qg, kg, vtw, projT, bm, out);
    } else {
        attn_kernel<<<2048, 256, 0, stream>>>(x, n1g, n1b, qkv_b, proj_b,
                                              qkvT, projT, biasT, maskT, out);
    }
    mlp3_kernel<<<1568, 256, 0, stream>>>(out, n2g, n2b, fc1_b, fc2_b, fc1T, fc2T);
}

// Round 4
// 502.633 us; speedup vs baseline: 1.9943x; 1.4655x over previous
//
#include <hip/hip_runtime.h>
#include <hip/hip_bf16.h>

// Swin block, round 4.
//  - lnqkv: LN1 + 3x [64,192]x[192,192] GEMM; outputs staged in LDS, flushed
//    as coalesced short8 stores to token-major qg (scaled), kg, vg.
//  - attnwin: stages window V^T into LDS once (1 barrier), then per-head
//    QK^T -> softmax -> PV -> proj accumulate. Frags direct from global.
//  - mlp3: unchanged (n-split waves, m_rep=4).
//  - fallback: round-2 monolithic attn if ws too small.

using f32x4  = __attribute__((ext_vector_type(4))) float;
using short8 = __attribute__((ext_vector_type(8))) short;
typedef unsigned short ushort_t;

__device__ __forceinline__ ushort_t f2bf(float f) {
    __hip_bfloat16 h = __float2bfloat16(f);
    return __builtin_bit_cast(ushort_t, h);
}
__device__ __forceinline__ f32x4 mfma16(short8 a, short8 b, f32x4 c) {
    return __builtin_amdgcn_mfma_f32_16x16x32_bf16(a, b, c, 0, 0, 0);
}

#define CC 192

// ws offsets (bytes)
#define OFF_QKVT   0          // [576][192] bf16
#define OFF_PROJT  221184     // [192][192] bf16
#define OFF_FC1T   294912     // [768][192] bf16
#define OFF_FC2T   589824     // [192][768] bf16
#define OFF_BIAS   884736     // [6][49][49] f32
#define OFF_MASK   942592     // [64][49][49] f32
#define OFF_BM     1557504    // [64][6][49][49] f32 fused bias+mask
#define OFF_QG     5245440    // [100352][192] bf16 (scaled Q)
#define OFF_KG     43780608   // [100352][192] bf16
#define OFF_VG     82315776   // [100352][192] bf16 (token-major V)
#define WS_NEED    120850944
#define PREP_SMALL 610438
#define PREP_BIG   1532422

// ---------------- prep ----------------
__global__ void prep_kernel(const float* __restrict__ qkv_w, const float* __restrict__ proj_w,
                            const float* __restrict__ fc1_w, const float* __restrict__ fc2_w,
                            const float* __restrict__ rel_table,
                            ushort_t* __restrict__ qkvT, ushort_t* __restrict__ projT,
                            ushort_t* __restrict__ fc1T, ushort_t* __restrict__ fc2T,
                            float* __restrict__ biasT, float* __restrict__ maskT,
                            float* __restrict__ bm, int full) {
    int idx = blockIdx.x * 256 + threadIdx.x;
    if (idx < 110592) { int n = idx / 192, k = idx % 192; qkvT[idx] = f2bf(qkv_w[k * 576 + n]); return; }
    idx -= 110592;
    if (idx < 36864) { int n = idx / 192, k = idx % 192; projT[idx] = f2bf(proj_w[k * 192 + n]); return; }
    idx -= 36864;
    if (idx < 147456) { int n = idx / 192, k = idx % 192; fc1T[idx] = f2bf(fc1_w[k * 768 + n]); return; }
    idx -= 147456;
    if (idx < 147456) { int n = idx / 768, k = idx % 768; fc2T[idx] = f2bf(fc2_w[k * 192 + n]); return; }
    idx -= 147456;
    if (idx < 14406) {
        int h = idx / 2401; int rest = idx % 2401; int a = rest / 49, b = rest % 49;
        int d = 13 * ((a % 7) - (b % 7) + (a / 7) - (b / 7) + 12);
        if (d > 168) d = 168;
        biasT[idx] = rel_table[d * 6 + h];
        return;
    }
    idx -= 14406;
    if (idx < 153664) {
        int w = idx / 2401; int rest = idx % 2401; int a = rest / 49, b = rest % 49;
        int wy = w / 8, wx = w % 8;
        int ya = wy * 7 + a / 7, xa = wx * 7 + a % 7;
        int yb = wy * 7 + b / 7, xb = wx * 7 + b % 7;
        int lya = ya < 49 ? 0 : (ya < 53 ? 1 : 2);
        int lxa = xa < 49 ? 0 : (xa < 53 ? 1 : 2);
        int lyb = yb < 49 ? 0 : (yb < 53 ? 1 : 2);
        int lxb = xb < 49 ? 0 : (xb < 53 ? 1 : 2);
        maskT[idx] = ((lya * 3 + lxa) != (lyb * 3 + lxb)) ? -100.0f : 0.0f;
        return;
    }
    idx -= 153664;
    if (full && idx < 921984) {  // bm[wi][h][a][b] = bias + mask
        int wi = idx / 14406; int r2 = idx % 14406;
        int h = r2 / 2401; int r3 = r2 % 2401;
        int a = r3 / 49, b = r3 % 49;
        int d = 13 * ((a % 7) - (b % 7) + (a / 7) - (b / 7) + 12);
        if (d > 168) d = 168;
        float bias = rel_table[d * 6 + h];
        int wy = wi / 8, wx = wi % 8;
        int ya = wy * 7 + a / 7, xa = wx * 7 + a % 7;
        int yb = wy * 7 + b / 7, xb = wx * 7 + b % 7;
        int lya = ya < 49 ? 0 : (ya < 53 ? 1 : 2);
        int lxa = xa < 49 ? 0 : (xa < 53 ? 1 : 2);
        int lyb = yb < 49 ? 0 : (yb < 53 ? 1 : 2);
        int lxb = xb < 49 ? 0 : (xb < 53 ? 1 : 2);
        float mask = ((lya * 3 + lxa) != (lyb * 3 + lxb)) ? -100.0f : 0.0f;
        bm[idx] = bias + mask;
        return;
    }
}

// ---------------- phase A: LN1 + QKV GEMM, coalesced writes ----------------
// 64 tokens/block (1568 blocks), 4 waves. Per v in {Q,K,V}: n-split GEMM
// (3 n-tiles/wave, m_rep=4) -> stage LDS -> flat coalesced flush.
__global__ __launch_bounds__(256, 3) void lnqkv_kernel(
    const float* __restrict__ x, const float* __restrict__ n1g, const float* __restrict__ n1b,
    const ushort_t* __restrict__ qkvT, const float* __restrict__ qkv_b,
    ushort_t* __restrict__ qg, ushort_t* __restrict__ kg, ushort_t* __restrict__ vg) {
    __shared__ ushort_t xln [64 * 200];
    __shared__ ushort_t qkvs[64 * 200];
    const int tid = threadIdx.x;
    const int wave = tid >> 6, lane = tid & 63;
    const int ln16 = lane & 15, sub = lane >> 4;
    const int t0 = blockIdx.x * 64;
    const f32x4 zero4 = {0.f, 0.f, 0.f, 0.f};

    for (int rr = 0; rr < 16; ++rr) {
        int row = wave * 16 + rr;
        const float* xr = x + (size_t)(t0 + row) * CC;
        float v0 = xr[lane], v1 = xr[lane + 64], v2 = xr[lane + 128];
        float s = v0 + v1 + v2;
        #pragma unroll
        for (int m = 32; m; m >>= 1) s += __shfl_xor(s, m);
        float mu = s * (1.0f / 192.0f);
        float d0 = v0 - mu, d1 = v1 - mu, d2 = v2 - mu;
        float q = d0 * d0 + d1 * d1 + d2 * d2;
        #pragma unroll
        for (int m = 32; m; m >>= 1) q += __shfl_xor(q, m);
        float rs = rsqrtf(q * (1.0f / 192.0f) + 1e-5f);
        xln[row * 200 + lane]       = f2bf(d0 * rs * n1g[lane]       + n1b[lane]);
        xln[row * 200 + lane + 64]  = f2bf(d1 * rs * n1g[lane + 64]  + n1b[lane + 64]);
        xln[row * 200 + lane + 128] = f2bf(d2 * rs * n1g[lane + 128] + n1b[lane + 128]);
    }
    __syncthreads();

    ushort_t* dsts[3] = {qg, kg, vg};
    for (int v = 0; v < 3; ++v) {
        f32x4 acc[4][3];
        #pragma unroll
        for (int m = 0; m < 4; ++m)
            #pragma unroll
            for (int n = 0; n < 3; ++n) acc[m][n] = zero4;
        for (int kk = 0; kk < 6; ++kk) {
            short8 a[4];
            #pragma unroll
            for (int m = 0; m < 4; ++m)
                a[m] = *(const short8*)(xln + (m * 16 + ln16) * 200 + kk * 32 + 8 * sub);
            #pragma unroll
            for (int n = 0; n < 3; ++n) {
                short8 b = *(const short8*)(qkvT + (size_t)(v * 192 + (wave * 3 + n) * 16 + ln16) * 192 + kk * 32 + 8 * sub);
                #pragma unroll
                for (int m = 0; m < 4; ++m) acc[m][n] = mfma16(a[m], b, acc[m][n]);
            }
        }
        // stage into LDS
        #pragma unroll
        for (int n = 0; n < 3; ++n) {
            int col = (wave * 3 + n) * 16 + ln16;
            float bv = qkv_b[v * 192 + col];
            #pragma unroll
            for (int m = 0; m < 4; ++m)
                #pragma unroll
                for (int r = 0; r < 4; ++r) {
                    int row = m * 16 + 4 * sub + r;
                    float val = acc[m][n][r] + bv;
                    if (v == 0) val *= 0.17677669529663689f;
                    qkvs[row * 200 + col] = f2bf(val);
                }
        }
        __syncthreads();
        // coalesced flush: 1536 short8s
        ushort_t* dst = dsts[v];
        for (int i = tid; i < 1536; i += 256) {
            int row = i / 24, c = i % 24;
            short8 vv = *(const short8*)(qkvs + row * 200 + c * 8);
            *(short8*)(dst + (size_t)(t0 + row) * 192 + c * 8) = vv;
        }
        __syncthreads();  // WAR on qkvs
    }
}

// ---------------- phase B: windowed attention ----------------
// 1 block/window (2048), 4 waves. V^T staged once in LDS (1 barrier), then
// barrier-free per-head loop. LDS: vt[192][72] + P[4][16][72] + O[4][16][72].
__global__ __launch_bounds__(256, 3) void attnwin_kernel(
    const float* __restrict__ x, const float* __restrict__ proj_b,
    const ushort_t* __restrict__ qg, const ushort_t* __restrict__ kg,
    const ushort_t* __restrict__ vg, const ushort_t* __restrict__ projT,
    const float* __restrict__ bm, float* __restrict__ out) {
    __shared__ ushort_t vt[192 * 72];
    __shared__ ushort_t Pl[4][16 * 72];
    __shared__ ushort_t oL[4][16 * 72];
    const int tid = threadIdx.x;
    const int wave = tid >> 6, lane = tid & 63;
    const int ln16 = lane & 15, sub = lane >> 4;
    const int win = blockIdx.x;
    const int b = win >> 6, wi = win & 63;
    const int wy = wi >> 3, wx = wi & 7;
    const f32x4 zero4 = {0.f, 0.f, 0.f, 0.f};

    // ---- stage V^T for this window ----
    {
        int j = tid & 63;
        int jj = j < 49 ? j : 48;
        int y  = wy * 7 + jj / 7 + 3; if (y >= 56) y -= 56;
        int xx = wx * 7 + jj % 7 + 3; if (xx >= 56) xx -= 56;
        size_t tokV = (size_t)(b * 3136 + y * 56 + xx);
        const bool valid = j < 49;
        #pragma unroll
        for (int pass = 0; pass < 6; ++pass) {
            int c8 = pass * 32 + (tid >> 6) * 8;
            if (valid) {
                short8 vv = *(const short8*)(vg + tokV * 192 + c8);
                #pragma unroll
                for (int q = 0; q < 8; ++q) vt[(c8 + q) * 72 + j] = ((ushort_t*)&vv)[q];
            } else {
                #pragma unroll
                for (int q = 0; q < 8; ++q) vt[(c8 + q) * 72 + j] = 0;
            }
        }
    }

    // A-frag token (this wave's row = ln16), clamped for pad rows
    size_t tokA;
    {
        int j = wave * 16 + ln16; if (j > 48) j = 48;
        int y  = wy * 7 + j / 7 + 3; if (y >= 56) y -= 56;
        int xx = wx * 7 + j % 7 + 3; if (xx >= 56) xx -= 56;
        tokA = (size_t)(b * 3136 + y * 56 + xx);
    }
    size_t tokB[4];
    #pragma unroll
    for (int n = 0; n < 4; ++n) {
        int j = n * 16 + ln16; if (j > 48) j = 48;
        int y  = wy * 7 + j / 7 + 3; if (y >= 56) y -= 56;
        int xx = wx * 7 + j % 7 + 3; if (xx >= 56) xx -= 56;
        tokB[n] = (size_t)(b * 3136 + y * 56 + xx);
    }

    f32x4 accP[12];
    #pragma unroll
    for (int n = 0; n < 12; ++n) accP[n] = zero4;

    ushort_t* Pw = Pl[wave];
    ushort_t* Ow = oL[wave];
    __syncthreads();  // vt ready

    for (int h = 0; h < 6; ++h) {
        // ---- S = QK^T (scale pre-folded into qg) ----
        short8 qf = *(const short8*)(qg + tokA * 192 + h * 32 + 8 * sub);
        f32x4 s4[4];
        #pragma unroll
        for (int n = 0; n < 4; ++n) {
            short8 kf = *(const short8*)(kg + tokB[n] * 192 + h * 32 + 8 * sub);
            s4[n] = mfma16(qf, kf, zero4);
        }
        // ---- + fused bias+mask ----
        const float* bmh = bm + (size_t)(wi * 6 + h) * 2401;
        #pragma unroll
        for (int n = 0; n < 4; ++n) {
            int col = n * 16 + ln16;
            #pragma unroll
            for (int r = 0; r < 4; ++r) {
                int row = wave * 16 + 4 * sub + r;
                s4[n][r] = (row < 49 && col < 49) ? s4[n][r] + bmh[row * 49 + col] : -1e30f;
            }
        }
        // ---- softmax ----
        #pragma unroll
        for (int r = 0; r < 4; ++r) {
            float mx = fmaxf(fmaxf(s4[0][r], s4[1][r]), fmaxf(s4[2][r], s4[3][r]));
            mx = fmaxf(mx, __shfl_xor(mx, 1, 16));
            mx = fmaxf(mx, __shfl_xor(mx, 2, 16));
            mx = fmaxf(mx, __shfl_xor(mx, 4, 16));
            mx = fmaxf(mx, __shfl_xor(mx, 8, 16));
            float e0 = __expf(s4[0][r] - mx), e1 = __expf(s4[1][r] - mx);
            float e2 = __expf(s4[2][r] - mx), e3 = __expf(s4[3][r] - mx);
            float sm = e0 + e1 + e2 + e3;
            sm += __shfl_xor(sm, 1, 16);
            sm += __shfl_xor(sm, 2, 16);
            sm += __shfl_xor(sm, 4, 16);
            sm += __shfl_xor(sm, 8, 16);
            float inv = 1.0f / sm;
            int rl = 4 * sub + r;
            Pw[rl * 72 +      ln16] = f2bf(e0 * inv);
            Pw[rl * 72 + 16 + ln16] = f2bf(e1 * inv);
            Pw[rl * 72 + 32 + ln16] = f2bf(e2 * inv);
            Pw[rl * 72 + 48 + ln16] = f2bf(e3 * inv);
        }
        // ---- PV ----
        f32x4 o2[2]; o2[0] = zero4; o2[1] = zero4;
        #pragma unroll
        for (int kk = 0; kk < 2; ++kk) {
            short8 ap = *(const short8*)(Pw + ln16 * 72 + kk * 32 + 8 * sub);
            #pragma unroll
            for (int n2 = 0; n2 < 2; ++n2) {
                short8 bv = *(const short8*)(vt + (h * 32 + n2 * 16 + ln16) * 72 + kk * 32 + 8 * sub);
                o2[n2] = mfma16(ap, bv, o2[n2]);
            }
        }
        #pragma unroll
        for (int n2 = 0; n2 < 2; ++n2)
            #pragma unroll
            for (int r = 0; r < 4; ++r)
                Ow[(4 * sub + r) * 72 + n2 * 16 + ln16] = f2bf(o2[n2][r]);
        // ---- proj partial accumulate ----
        {
            short8 ao = *(const short8*)(Ow + ln16 * 72 + 8 * sub);
            #pragma unroll
            for (int n = 0; n < 12; ++n) {
                short8 bp = *(const short8*)(projT + (size_t)(n * 16 + ln16) * 192 + h * 32 + 8 * sub);
                accP[n] = mfma16(ao, bp, accP[n]);
            }
        }
    }

    // ---- epilogue: + proj bias + residual, scatter ----
    #pragma unroll
    for (int n = 0; n < 12; ++n) {
        int col = n * 16 + ln16;
        float pb = proj_b[col];
        #pragma unroll
        for (int r = 0; r < 4; ++r) {
            int row = wave * 16 + 4 * sub + r;
            if (row < 49) {
                int y  = wy * 7 + row / 7 + 3; if (y >= 56) y -= 56;
                int xx = wx * 7 + row % 7 + 3; if (xx >= 56) xx -= 56;
                size_t g = (size_t)(b * 3136 + y * 56 + xx) * CC;
                out[g + col] = accP[n][r] + pb + x[g + col];
            }
        }
    }
}

// ---------------- fallback: round-2 monolithic attention ----------------
__global__ __launch_bounds__(256, 3) void attn_kernel(
    const float* __restrict__ x, const float* __restrict__ n1g, const float* __restrict__ n1b,
    const float* __restrict__ qkv_b, const float* __restrict__ proj_b,
    const ushort_t* __restrict__ qkvT, const ushort_t* __restrict__ projT,
    const float* __restrict__ biasT, const float* __restrict__ maskT,
    float* __restrict__ out) {
    __shared__ ushort_t xln[64 * 200];
    __shared__ ushort_t qo [64 * 40];
    __shared__ ushort_t kl [64 * 40];
    __shared__ ushort_t vt [32 * 72];
    __shared__ ushort_t Pl [64 * 72];
    const int tid = threadIdx.x;
    const int wave = tid >> 6, lane = tid & 63;
    const int ln16 = lane & 15, sub = lane >> 4;
    const int w = blockIdx.x;
    const int batch = w >> 6, wi = w & 63;
    const int wy = wi >> 3, wx = wi & 7;
    const f32x4 zero4 = {0.f, 0.f, 0.f, 0.f};

    for (int rr = 0; rr < 16; ++rr) {
        int row = wave * 16 + rr;
        if (row < 49) {
            int ty = row / 7, tx = row % 7;
            int y  = wy * 7 + ty + 3; if (y >= 56) y -= 56;
            int xx = wx * 7 + tx + 3; if (xx >= 56) xx -= 56;
            const float* xr = x + (size_t)(batch * 3136 + y * 56 + xx) * CC;
            float v0 = xr[lane], v1 = xr[lane + 64], v2 = xr[lane + 128];
            float s = v0 + v1 + v2;
            #pragma unroll
            for (int m = 32; m; m >>= 1) s += __shfl_xor(s, m);
            float mu = s * (1.0f / 192.0f);
            float d0 = v0 - mu, d1 = v1 - mu, d2 = v2 - mu;
            float q = d0 * d0 + d1 * d1 + d2 * d2;
            #pragma unroll
            for (int m = 32; m; m >>= 1) q += __shfl_xor(q, m);
            float rs = rsqrtf(q * (1.0f / 192.0f) + 1e-5f);
            xln[row * 200 + lane]       = f2bf(d0 * rs * n1g[lane]       + n1b[lane]);
            xln[row * 200 + lane + 64]  = f2bf(d1 * rs * n1g[lane + 64]  + n1b[lane + 64]);
            xln[row * 200 + lane + 128] = f2bf(d2 * rs * n1g[lane + 128] + n1b[lane + 128]);
        } else {
            xln[row * 200 + lane] = 0; xln[row * 200 + lane + 64] = 0; xln[row * 200 + lane + 128] = 0;
        }
    }

    f32x4 accP[12];
    #pragma unroll
    for (int n = 0; n < 12; ++n) accP[n] = zero4;
    const float scale = 0.17677669529663689f;
    const float* mptr = maskT + wi * 2401;

    for (int h = 0; h < 6; ++h) {
        f32x4 acc6[6];
        #pragma unroll
        for (int n = 0; n < 6; ++n) acc6[n] = zero4;
        const int cb0 = h * 32;
        for (int kk = 0; kk < 6; ++kk) {
            short8 a = *(const short8*)(xln + (wave * 16 + ln16) * 200 + kk * 32 + 8 * sub);
            #pragma unroll
            for (int n = 0; n < 6; ++n) {
                int colbase = (n >> 1) * 192 + cb0 + (n & 1) * 16;
                short8 b = *(const short8*)(qkvT + (size_t)(colbase + ln16) * 192 + kk * 32 + 8 * sub);
                acc6[n] = mfma16(a, b, acc6[n]);
            }
        }
        #pragma unroll
        for (int n = 0; n < 6; ++n) {
            int colbase = (n >> 1) * 192 + cb0 + (n & 1) * 16;
            float bv = qkv_b[colbase + ln16];
            int dim = (n & 1) * 16 + ln16;
            #pragma unroll
            for (int r = 0; r < 4; ++r) {
                int row = wave * 16 + 4 * sub + r;
                ushort_t hv = f2bf(acc6[n][r] + bv);
                if (n < 2)      qo[row * 40 + dim] = hv;
                else if (n < 4) kl[row * 40 + dim] = hv;
                else            vt[dim * 72 + row] = hv;
            }
        }
        __syncthreads();

        f32x4 s4[4];
        {
            short8 aq = *(const short8*)(qo + (wave * 16 + ln16) * 40 + 8 * sub);
            #pragma unroll
            for (int n = 0; n < 4; ++n) {
                short8 bk = *(const short8*)(kl + (n * 16 + ln16) * 40 + 8 * sub);
                s4[n] = mfma16(aq, bk, zero4);
            }
        }
        const float* bptr = biasT + h * 2401;
        #pragma unroll
        for (int n = 0; n < 4; ++n) {
            int col = n * 16 + ln16;
            #pragma unroll
            for (int r = 0; r < 4; ++r) {
                int row = wave * 16 + 4 * sub + r;
                s4[n][r] = (row < 49 && col < 49)
                    ? s4[n][r] * scale + bptr[row * 49 + col] + mptr[row * 49 + col]
                    : -1e30f;
            }
        }
        #pragma unroll
        for (int r = 0; r < 4; ++r) {
            float mx = fmaxf(fmaxf(s4[0][r], s4[1][r]), fmaxf(s4[2][r], s4[3][r]));
            mx = fmaxf(mx, __shfl_xor(mx, 1, 16));
            mx = fmaxf(mx, __shfl_xor(mx, 2, 16));
            mx = fmaxf(mx, __shfl_xor(mx, 4, 16));
            mx = fmaxf(mx, __shfl_xor(mx, 8, 16));
            float e0 = __expf(s4[0][r] - mx), e1 = __expf(s4[1][r] - mx);
            float e2 = __expf(s4[2][r] - mx), e3 = __expf(s4[3][r] - mx);
            float sm = e0 + e1 + e2 + e3;
            sm += __shfl_xor(sm, 1, 16);
            sm += __shfl_xor(sm, 2, 16);
            sm += __shfl_xor(sm, 4, 16);
            sm += __shfl_xor(sm, 8, 16);
            float inv = 1.0f / sm;
            int row = wave * 16 + 4 * sub + r;
            Pl[row * 72 +      ln16] = f2bf(e0 * inv);
            Pl[row * 72 + 16 + ln16] = f2bf(e1 * inv);
            Pl[row * 72 + 32 + ln16] = f2bf(e2 * inv);
            Pl[row * 72 + 48 + ln16] = f2bf(e3 * inv);
        }
        f32x4 o2[2]; o2[0] = zero4; o2[1] = zero4;
        #pragma unroll
        for (int ks = 0; ks < 2; ++ks) {
            short8 ap = *(const short8*)(Pl + (wave * 16 + ln16) * 72 + ks * 32 + 8 * sub);
            #pragma unroll
            for (int n2 = 0; n2 < 2; ++n2) {
                short8 bv = *(const short8*)(vt + (n2 * 16 + ln16) * 72 + ks * 32 + 8 * sub);
                o2[n2] = mfma16(ap, bv, o2[n2]);
            }
        }
        #pragma unroll
        for (int n2 = 0; n2 < 2; ++n2)
            #pragma unroll
            for (int r = 0; r < 4; ++r) {
                int row = wave * 16 + 4 * sub + r;
                qo[row * 40 + n2 * 16 + ln16] = f2bf(o2[n2][r]);
            }
        {
            short8 ao = *(const short8*)(qo + (wave * 16 + ln16) * 40 + 8 * sub);
            #pragma unroll
            for (int n = 0; n < 12; ++n) {
                short8 bp = *(const short8*)(projT + (size_t)(n * 16 + ln16) * 192 + h * 32 + 8 * sub);
                accP[n] = mfma16(ao, bp, accP[n]);
            }
        }
        __syncthreads();
    }

    #pragma unroll
    for (int n = 0; n < 12; ++n) {
        int col = n * 16 + ln16;
        float pb = proj_b[col];
        #pragma unroll
        for (int r = 0; r < 4; ++r) {
            int row = wave * 16 + 4 * sub + r;
            if (row < 49) {
                int ty = row / 7, tx = row % 7;
                int y  = wy * 7 + ty + 3; if (y >= 56) y -= 56;
                int xx = wx * 7 + tx + 3; if (xx >= 56) xx -= 56;
                size_t g = (size_t)(batch * 3136 + y * 56 + xx) * CC;
                out[g + col] = accP[n][r] + pb + x[g + col];
            }
        }
    }
}

// ---------------- MLP v3: n-split waves, m_rep=4 ----------------
__global__ __launch_bounds__(256, 3) void mlp3_kernel(
    float* __restrict__ out, const float* __restrict__ n2g, const float* __restrict__ n2b,
    const float* __restrict__ fc1_b, const float* __restrict__ fc2_b,
    const ushort_t* __restrict__ fc1T, const ushort_t* __restrict__ fc2T) {
    __shared__ ushort_t aln [64 * 200];
    __shared__ ushort_t hidc[64 * 136];
    const int tid = threadIdx.x;
    const int wave = tid >> 6, lane = tid & 63;
    const int ln16 = lane & 15, sub = lane >> 4;
    const size_t t0 = (size_t)blockIdx.x * 64;
    const f32x4 zero4 = {0.f, 0.f, 0.f, 0.f};

    for (int rr = 0; rr < 16; ++rr) {
        int row = wave * 16 + rr;
        const float* xr = out + (t0 + row) * CC;
        float v0 = xr[lane], v1 = xr[lane + 64], v2 = xr[lane + 128];
        float s = v0 + v1 + v2;
        #pragma unroll
        for (int m = 32; m; m >>= 1) s += __shfl_xor(s, m);
        float mu = s * (1.0f / 192.0f);
        float d0 = v0 - mu, d1 = v1 - mu, d2 = v2 - mu;
        float q = d0 * d0 + d1 * d1 + d2 * d2;
        #pragma unroll
        for (int m = 32; m; m >>= 1) q += __shfl_xor(q, m);
        float rs = rsqrtf(q * (1.0f / 192.0f) + 1e-5f);
        aln[row * 200 + lane]       = f2bf(d0 * rs * n2g[lane]       + n2b[lane]);
        aln[row * 200 + lane + 64]  = f2bf(d1 * rs * n2g[lane + 64]  + n2b[lane + 64]);
        aln[row * 200 + lane + 128] = f2bf(d2 * rs * n2g[lane + 128] + n2b[lane + 128]);
    }
    __syncthreads();

    f32x4 accO[4][3];
    #pragma unroll
    for (int m = 0; m < 4; ++m)
        #pragma unroll
        for (int n = 0; n < 3; ++n) accO[m][n] = zero4;

    for (int c = 0; c < 6; ++c) {
        f32x4 acc1[4][2];
        #pragma unroll
        for (int m = 0; m < 4; ++m)
            #pragma unroll
            for (int n = 0; n < 2; ++n) acc1[m][n] = zero4;
        for (int kk = 0; kk < 6; ++kk) {
            short8 a[4];
            #pragma unroll
            for (int m = 0; m < 4; ++m)
                a[m] = *(const short8*)(aln + (m * 16 + ln16) * 200 + kk * 32 + 8 * sub);
            #pragma unroll
            for (int n = 0; n < 2; ++n) {
                short8 b = *(const short8*)(fc1T + (size_t)(c * 128 + wave * 32 + n * 16 + ln16) * 192 + kk * 32 + 8 * sub);
                #pragma unroll
                for (int m = 0; m < 4; ++m) acc1[m][n] = mfma16(a[m], b, acc1[m][n]);
            }
        }
        #pragma unroll
        for (int n = 0; n < 2; ++n) {
            int cl = wave * 32 + n * 16 + ln16;
            float fb = fc1_b[c * 128 + cl];
            #pragma unroll
            for (int m = 0; m < 4; ++m)
                #pragma unroll
                for (int r = 0; r < 4; ++r) {
                    float hv = acc1[m][n][r] + fb;
                    float ge = 0.5f * hv * (1.0f + erff(hv * 0.70710678118654752f));
                    hidc[(m * 16 + 4 * sub + r) * 136 + cl] = f2bf(ge);
                }
        }
        __syncthreads();
        #pragma unroll
        for (int kk = 0; kk < 4; ++kk) {
            short8 a[4];
            #pragma unroll
            for (int m = 0; m < 4; ++m)
                a[m] = *(const short8*)(hidc + (m * 16 + ln16) * 136 + kk * 32 + 8 * sub);
            #pragma unroll
            for (int n = 0; n < 3; ++n) {
                short8 b = *(const short8*)(fc2T + (size_t)(wave * 48 + n * 16 + ln16) * 768 + c * 128 + kk * 32 + 8 * sub);
                #pragma unroll
                for (int m = 0; m < 4; ++m) accO[m][n] = mfma16(a[m], b, accO[m][n]);
            }
        }
        __syncthreads();
    }

    #pragma unroll
    for (int n = 0; n < 3; ++n) {
        int col = wave * 48 + n * 16 + ln16;
        float fb = fc2_b[col];
        #pragma unroll
        for (int m = 0; m < 4; ++m)
            #pragma unroll
            for (int r = 0; r < 4; ++r) {
                size_t o = (t0 + m * 16 + 4 * sub + r) * CC + col;
                out[o] = accO[m][n][r] + fb + out[o];
            }
    }
}

// ---------------- launch ----------------
extern "C" void kernel_launch(void* const* d_in, const int* in_sizes, int n_in,
                              void* d_out, int out_size, void* d_ws, size_t ws_size,
                              hipStream_t stream) {
    const float* x      = (const float*)d_in[0];
    const float* n1g    = (const float*)d_in[1];
    const float* n1b    = (const float*)d_in[2];
    const float* qkv_w  = (const float*)d_in[3];
    const float* qkv_b  = (const float*)d_in[4];
    const float* rel_t  = (const float*)d_in[5];
    const float* proj_w = (const float*)d_in[6];
    const float* proj_b = (const float*)d_in[7];
    const float* n2g    = (const float*)d_in[8];
    const float* n2b    = (const float*)d_in[9];
    const float* fc1_w  = (const float*)d_in[10];
    const float* fc1_b  = (const float*)d_in[11];
    const float* fc2_w  = (const float*)d_in[12];
    const float* fc2_b  = (const float*)d_in[13];
    float* out = (float*)d_out;

    char* ws = (char*)d_ws;
    ushort_t* qkvT  = (ushort_t*)(ws + OFF_QKVT);
    ushort_t* projT = (ushort_t*)(ws + OFF_PROJT);
    ushort_t* fc1T  = (ushort_t*)(ws + OFF_FC1T);
    ushort_t* fc2T  = (ushort_t*)(ws + OFF_FC2T);
    float* biasT    = (float*)(ws + OFF_BIAS);
    float* maskT    = (float*)(ws + OFF_MASK);
    float* bm       = (float*)(ws + OFF_BM);
    ushort_t* qg    = (ushort_t*)(ws + OFF_QG);
    ushort_t* kg    = (ushort_t*)(ws + OFF_KG);
    ushort_t* vg    = (ushort_t*)(ws + OFF_VG);

    const int big = ws_size >= (size_t)WS_NEED;
    const int prep_total = big ? PREP_BIG : PREP_SMALL;
    prep_kernel<<<(prep_total + 255) / 256, 256, 0, stream>>>(
        qkv_w, proj_w, fc1_w, fc2_w, rel_t, qkvT, projT, fc1T, fc2T, biasT, maskT, bm, big);

    if (big) {
        lnqkv_kernel<<<1568, 256, 0, stream>>>(x, n1g, n1b, qkvT, qkv_b, qg, kg, vg);
        attnwin_kernel<<<2048, 256, 0, stream>>>(x, proj_b, qg, kg, vg, projT, bm, out);
    } else {
        attn_kernel<<<2048, 256, 0, stream>>>(x, n1g, n1b, qkv_b, proj_b,
                                              qkvT, projT, biasT, maskT, out);
    }
    mlp3_kernel<<<1568, 256, 0, stream>>>(out, n2g, n2b, fc1_b, fc2_b, fc1T, fc2T);
}